// Round 2
// baseline (191.064 us; speedup 1.0000x reference)
//
#include <hip/hip_runtime.h>

// ---------------------------------------------------------------------------
// CausalAttention: out = softmax(mask(QK^T/sqrt(D))) @ V,  Q/K/V = x @ W_{q,k,v}
// B=4, S=2048, D_IN=D_OUT=1024, fp32 in/out, bf16 MFMA internally.
// ---------------------------------------------------------------------------

typedef __bf16 bf16x8 __attribute__((ext_vector_type(8)));
typedef float f32x4 __attribute__((ext_vector_type(4)));

__device__ __forceinline__ unsigned short f2bf(float f) {
  unsigned int u = __builtin_bit_cast(unsigned int, f);
  u += 0x7FFFu + ((u >> 16) & 1u);  // RNE
  return (unsigned short)(u >> 16);
}
__device__ __forceinline__ float bf2f(unsigned short h) {
  unsigned int u = ((unsigned int)h) << 16;
  return __builtin_bit_cast(float, u);
}

#define GLDS16(g, l)                                                                   \
  __builtin_amdgcn_global_load_lds((const __attribute__((address_space(1))) void*)(g), \
                                   (__attribute__((address_space(3))) void*)(l), 16, 0, 0)

// ---------------- fp32 -> bf16 convert (vectorized) ----------------
__global__ __launch_bounds__(256) void k_cvt(const float* __restrict__ in,
                                             unsigned short* __restrict__ out, long n) {
  long i = ((long)blockIdx.x * 256 + threadIdx.x) * 4;
  if (i >= n) return;  // n is a multiple of 4
  float4 f = *(const float4*)(in + i);
  uint2 o;
  o.x = (unsigned)f2bf(f.x) | ((unsigned)f2bf(f.y) << 16);
  o.y = (unsigned)f2bf(f.z) | ((unsigned)f2bf(f.w) << 16);
  *(uint2*)(out + i) = o;
}

// ---------------- W[k][n] fp32 -> Wt[n][k] bf16 (3 weights via grid.z) ------
__global__ void k_trans_w(const float* __restrict__ W0, const float* __restrict__ W1,
                          const float* __restrict__ W2, unsigned short* __restrict__ Wt, int D) {
  const float* W = blockIdx.z == 0 ? W0 : (blockIdx.z == 1 ? W1 : W2);
  unsigned short* out = Wt + (long)blockIdx.z * D * D;
  __shared__ float tile[32][33];
  int tx = threadIdx.x, ty = threadIdx.y;  // (32,8)
  int bx = blockIdx.x * 32, by = blockIdx.y * 32;
#pragma unroll
  for (int j = 0; j < 4; ++j) tile[ty + j * 8][tx] = W[(long)(by + ty + j * 8) * D + bx + tx];
  __syncthreads();
#pragma unroll
  for (int j = 0; j < 4; ++j)
    out[(long)(bx + ty + j * 8) * D + by + tx] = f2bf(tile[tx][ty + j * 8]);
}

// ---------------- bf16 transpose: Vb[s][f] -> Vt[f][s] (per batch z) --------
__global__ void k_trans_v(const unsigned short* __restrict__ Vb, unsigned short* __restrict__ Vt,
                          int S, int D) {
  const unsigned short* in = Vb + (long)blockIdx.z * S * D;
  unsigned short* out = Vt + (long)blockIdx.z * S * D;
  __shared__ unsigned short tile[32][33];
  int tx = threadIdx.x, ty = threadIdx.y;  // (32,8)
  int bx = blockIdx.x * 32;  // over D (f)
  int by = blockIdx.y * 32;  // over S (s)
#pragma unroll
  for (int j = 0; j < 4; ++j) tile[ty + j * 8][tx] = in[(long)(by + ty + j * 8) * D + bx + tx];
  __syncthreads();
#pragma unroll
  for (int j = 0; j < 4; ++j)
    out[(long)(bx + ty + j * 8) * S + by + tx] = tile[tx][ty + j * 8];
}

// ---------------- BT GEMM: C[m][n] = alpha * sum_k A[m][k] * B[n][k] --------
// m97 structure: 128x128 tile, BK=64, 4 waves (2x2, 64x64 each), 16x16x32 MFMA,
// global_load_lds width 16 with XOR chunk-swizzle pre-applied on the global
// source (LDS dest stays linear), same swizzle on ds_read -> 2-way conflicts (free).
// SKIPN: skip output blocks entirely above the causal diagonal (scores GEMM).
// LIMK:  clamp K-tiles to the causal diagonal of the row block (PV GEMM; P is
//        zero beyond the diagonal).
template <typename CT, bool SKIPN, bool LIMK>
__global__ __launch_bounds__(256) void k_gemm_bt(const unsigned short* __restrict__ A,
                                                 const unsigned short* __restrict__ B,
                                                 CT* __restrict__ C, int M, int N, int K, long sA,
                                                 long sB, long sC, float alpha) {
  const int m0 = blockIdx.y * 128;
  const int n0 = blockIdx.x * 128;
  if (SKIPN && n0 > m0 + 127) return;  // uniform per block: safe early-out
  A += (long)blockIdx.z * sA;
  B += (long)blockIdx.z * sB;
  C += (long)blockIdx.z * sC;

  __shared__ unsigned short As[128 * 64];
  __shared__ unsigned short Bs[128 * 64];
  char* const AsB = (char*)As;
  char* const BsB = (char*)Bs;

  const int t = threadIdx.x;
  const int l = t & 63;
  const int w = t >> 6;
  const int wr = (w >> 1) * 64;  // wave row base in tile
  const int wc = (w & 1) * 64;   // wave col base in tile

  // Staging map: LDS byte o = i*4096 + t*16 -> row = i*32 + t/8, phys chunk = t&7.
  // Logical chunk c = phys ^ (row&7) = (t&7) ^ ((t>>3)&7)  (i*32 ≡ 0 mod 8).
  const int srow = t >> 3;
  const int sch = (t & 7) ^ (srow & 7);
  const unsigned short* Ag = A + (long)(m0 + srow) * K + sch * 8;
  const unsigned short* Bg = B + (long)(n0 + srow) * K + sch * 8;
  const int soff = t * 16;

  const int ar = wr + (l & 15);   // A-frag row (within tile)
  const int brr = wc + (l & 15);  // B-frag row
  const int kc = l >> 4;          // k-chunk within 32-k step

  f32x4 acc[4][4];
#pragma unroll
  for (int i = 0; i < 4; ++i)
#pragma unroll
    for (int j = 0; j < 4; ++j) acc[i][j] = f32x4{0.f, 0.f, 0.f, 0.f};

  int KT = K >> 6;
  if (LIMK) {
    int kt2 = (m0 + 128) >> 6;
    KT = KT < kt2 ? KT : kt2;
  }

  for (int kt = 0; kt < KT; ++kt) {
    const long ko = (long)kt * 64;
#pragma unroll
    for (int i = 0; i < 4; ++i) GLDS16(Ag + (long)i * 32 * K + ko, AsB + i * 4096 + soff);
#pragma unroll
    for (int i = 0; i < 4; ++i) GLDS16(Bg + (long)i * 32 * K + ko, BsB + i * 4096 + soff);
    __syncthreads();  // compiler emits s_waitcnt vmcnt(0) before s_barrier
#pragma unroll
    for (int kk = 0; kk < 2; ++kk) {
      bf16x8 av[4], bv[4];
#pragma unroll
      for (int m = 0; m < 4; ++m) {
        int r = ar + m * 16;
        int c = (kk * 4 + kc) ^ (r & 7);
        av[m] = *(const bf16x8*)(AsB + r * 128 + c * 16);
      }
#pragma unroll
      for (int n = 0; n < 4; ++n) {
        int r = brr + n * 16;
        int c = (kk * 4 + kc) ^ (r & 7);
        bv[n] = *(const bf16x8*)(BsB + r * 128 + c * 16);
      }
#pragma unroll
      for (int m = 0; m < 4; ++m)
#pragma unroll
        for (int n = 0; n < 4; ++n)
          acc[m][n] = __builtin_amdgcn_mfma_f32_16x16x32_bf16(av[m], bv[n], acc[m][n], 0, 0, 0);
    }
    __syncthreads();
  }

  // C/D layout (m89-verified): col = lane&15, row = (lane>>4)*4 + reg
  const int rb = m0 + wr + (l >> 4) * 4;
  const int cb = n0 + wc + (l & 15);
#pragma unroll
  for (int m = 0; m < 4; ++m)
#pragma unroll
    for (int n = 0; n < 4; ++n)
#pragma unroll
      for (int i = 0; i < 4; ++i) {
        float v = acc[m][n][i] * alpha;
        long off = (long)(rb + m * 16 + i) * N + (cb + n * 16);
        if constexpr (sizeof(CT) == 2)
          C[off] = f2bf(v);
        else
          C[off] = v;
      }
}

// ---------------- causal row softmax, in-place on bf16 P --------------------
// One block per row; writes ALL 2048 cols (zeros beyond diagonal — buffer was
// poisoned and upper score blocks were never written).
__global__ __launch_bounds__(256) void k_softmax(unsigned short* __restrict__ P, int S) {
  const int q = blockIdx.x;
  unsigned short* row = P + ((long)blockIdx.y * S + q) * S;
  const int t = threadIdx.x;
  const int c0 = t * 8;
  uint4 raw = ((const uint4*)row)[t];
  unsigned int rw[4] = {raw.x, raw.y, raw.z, raw.w};
  float v[8];
#pragma unroll
  for (int j = 0; j < 8; ++j) v[j] = bf2f((unsigned short)((rw[j >> 1] >> ((j & 1) * 16)) & 0xFFFF));

  float mx = -3.0e38f;
#pragma unroll
  for (int j = 0; j < 8; ++j)
    if (c0 + j <= q) mx = fmaxf(mx, v[j]);
#pragma unroll
  for (int o = 32; o >= 1; o >>= 1) mx = fmaxf(mx, __shfl_xor(mx, o, 64));
  __shared__ float redm[4], reds[4];
  const int wv = t >> 6;
  if ((t & 63) == 0) redm[wv] = mx;
  __syncthreads();
  mx = fmaxf(fmaxf(redm[0], redm[1]), fmaxf(redm[2], redm[3]));

  float e[8], s = 0.f;
#pragma unroll
  for (int j = 0; j < 8; ++j) {
    e[j] = (c0 + j <= q) ? __expf(v[j] - mx) : 0.f;
    s += e[j];
  }
#pragma unroll
  for (int o = 32; o >= 1; o >>= 1) s += __shfl_xor(s, o, 64);
  if ((t & 63) == 0) reds[wv] = s;
  __syncthreads();
  s = reds[0] + reds[1] + reds[2] + reds[3];
  const float inv = 1.f / s;

  uint4 ow;
  unsigned int o2[4];
#pragma unroll
  for (int jj = 0; jj < 4; ++jj)
    o2[jj] = (unsigned)f2bf(e[2 * jj] * inv) | ((unsigned)f2bf(e[2 * jj + 1] * inv) << 16);
  ow.x = o2[0]; ow.y = o2[1]; ow.z = o2[2]; ow.w = o2[3];
  ((uint4*)row)[t] = ow;
}

// ---------------------------------------------------------------------------
extern "C" void kernel_launch(void* const* d_in, const int* in_sizes, int n_in, void* d_out,
                              int out_size, void* d_ws, size_t ws_size, hipStream_t stream) {
  const int B = 4, S = 2048, D = 1024;
  const long MS = (long)B * S;  // 8192 flattened tokens

  const float* x = (const float*)d_in[0];
  const float* Wq = (const float*)d_in[1];
  const float* Wk = (const float*)d_in[2];
  const float* Wv = (const float*)d_in[3];
  float* out = (float*)d_out;

  // workspace layout (elements of ushort); total 123,731,968 bytes (~118 MB)
  unsigned short* xb = (unsigned short*)d_ws;   // [8192][1024]
  unsigned short* Wt = xb + MS * D;             // 3 x [1024][1024] (transposed)
  unsigned short* Qb = Wt + 3L * D * D;         // [8192][1024]
  unsigned short* Kb = Qb + MS * D;             // [8192][1024]
  unsigned short* Vb = Kb + MS * D;             // [8192][1024]
  unsigned short* Vt = Vb + MS * D;             // 4 x [1024][2048]
  unsigned short* P  = Vt + MS * D;             // 4 x [2048][2048] scores->probs
  (void)ws_size;

  // 1) x -> bf16
  long n = MS * D;
  k_cvt<<<dim3((unsigned)(n / 4 / 256)), 256, 0, stream>>>(x, xb, n);
  // 2) W -> bf16 transposed [n][k]
  k_trans_w<<<dim3(32, 32, 3), dim3(32, 8), 0, stream>>>(Wq, Wk, Wv, Wt, D);
  // 3) projections: {Q,K,V}b = xb @ Wt^T   (grid.z selects weight & output)
  k_gemm_bt<unsigned short, false, false><<<dim3(D / 128, MS / 128, 3), 256, 0, stream>>>(
      xb, Wt, Qb, (int)MS, D, D, 0L, (long)D * D, MS * D, 1.0f);
  // 4) V -> V^T per batch
  k_trans_v<<<dim3(D / 32, S / 32, B), dim3(32, 8), 0, stream>>>(Vb, Vt, S, D);
  // 5) scores: P = (Q @ K^T) / 32, skipping fully-masked blocks
  k_gemm_bt<unsigned short, true, false><<<dim3(S / 128, S / 128, B), 256, 0, stream>>>(
      Qb, Kb, P, S, S, D, (long)S * D, (long)S * D, (long)S * S, 0.03125f);
  // 6) causal softmax rows (writes zeros above diagonal)
  k_softmax<<<dim3(S, B), 256, 0, stream>>>(P, S);
  // 7) out = P @ V  (K-tiles clamped at the diagonal)
  k_gemm_bt<float, false, true><<<dim3(D / 128, S / 128, B), 256, 0, stream>>>(
      P, Vt, out, S, D, S, (long)S * S, (long)S * D, (long)S * D, 1.0f);
}

// Round 3
// 176.736 us; speedup vs baseline: 1.0811x; 1.0811x over previous
//
#include <hip/hip_runtime.h>

// ---------------------------------------------------------------------------
// CausalAttention: out = softmax(mask(QK^T/sqrt(D))) @ V,  Q/K/V = x @ W_{q,k,v}
// B=4, S=2048, D_IN=D_OUT=1024, fp32 in/out, bf16 MFMA internally.
// R2: +XCD-chunk swizzle on all GEMMs (T1), V^T produced directly by GEMM
// (trans_v eliminated), wave-per-row softmax.
// ---------------------------------------------------------------------------

typedef __bf16 bf16x8 __attribute__((ext_vector_type(8)));
typedef float f32x4 __attribute__((ext_vector_type(4)));

__device__ __forceinline__ unsigned short f2bf(float f) {
  unsigned int u = __builtin_bit_cast(unsigned int, f);
  u += 0x7FFFu + ((u >> 16) & 1u);  // RNE
  return (unsigned short)(u >> 16);
}
__device__ __forceinline__ float bf2f(unsigned short h) {
  unsigned int u = ((unsigned int)h) << 16;
  return __builtin_bit_cast(float, u);
}

#define GLDS16(g, l)                                                                   \
  __builtin_amdgcn_global_load_lds((const __attribute__((address_space(1))) void*)(g), \
                                   (__attribute__((address_space(3))) void*)(l), 16, 0, 0)

// ---------------- fp32 -> bf16 convert (8 elems/lane) ----------------
__global__ __launch_bounds__(256) void k_cvt(const float* __restrict__ in,
                                             unsigned short* __restrict__ out, long n) {
  long i = ((long)blockIdx.x * 256 + threadIdx.x) * 8;
  if (i >= n) return;  // n is a multiple of 8
  float4 a = *(const float4*)(in + i);
  float4 b = *(const float4*)(in + i + 4);
  uint4 o;
  o.x = (unsigned)f2bf(a.x) | ((unsigned)f2bf(a.y) << 16);
  o.y = (unsigned)f2bf(a.z) | ((unsigned)f2bf(a.w) << 16);
  o.z = (unsigned)f2bf(b.x) | ((unsigned)f2bf(b.y) << 16);
  o.w = (unsigned)f2bf(b.z) | ((unsigned)f2bf(b.w) << 16);
  *(uint4*)(out + i) = o;
}

// ---------------- W[k][n] fp32 -> Wt[n][k] bf16 (3 weights via grid.z) ------
__global__ void k_trans_w(const float* __restrict__ W0, const float* __restrict__ W1,
                          const float* __restrict__ W2, unsigned short* __restrict__ Wt, int D) {
  const float* W = blockIdx.z == 0 ? W0 : (blockIdx.z == 1 ? W1 : W2);
  unsigned short* out = Wt + (long)blockIdx.z * D * D;
  __shared__ float tile[32][33];
  int tx = threadIdx.x, ty = threadIdx.y;  // (32,8)
  int bx = blockIdx.x * 32, by = blockIdx.y * 32;
#pragma unroll
  for (int j = 0; j < 4; ++j) tile[ty + j * 8][tx] = W[(long)(by + ty + j * 8) * D + bx + tx];
  __syncthreads();
#pragma unroll
  for (int j = 0; j < 4; ++j)
    out[(long)(bx + ty + j * 8) * D + by + tx] = f2bf(tile[tx][ty + j * 8]);
}

// ---------------- BT GEMM: C[m][n] = alpha * sum_k A[m][k] * B[n][k] --------
// m97 structure: 128x128 tile, BK=64, 4 waves (2x2, 64x64 each), 16x16x32 MFMA,
// global_load_lds width 16, source-side XOR chunk-swizzle (LDS linear),
// measured SQ_LDS_BANK_CONFLICT == 0.
// 1-D flattened grid with bijective XCD-chunk swizzle (T1): hw block b ->
// logical (b%8)*cpx + b/8, so each XCD's L2 sees a contiguous run of m-tiles
// (A reused 8-24x in-L2). Requires gridDim.x % 8 == 0 (all call sites comply).
// SKIPN: skip output blocks above the causal diagonal (scores GEMM).
// LIMK:  clamp K-tiles to the causal diagonal of the row block (PV GEMM).
template <typename CT, bool SKIPN, bool LIMK>
__global__ __launch_bounds__(256) void k_gemm_bt(const unsigned short* __restrict__ A,
                                                 const unsigned short* __restrict__ B,
                                                 CT* __restrict__ C, int nx, int ny, int N, int K,
                                                 long sA, long sB, long sC, float alpha) {
  // XCD-aware decode
  const unsigned bid = blockIdx.x;
  const unsigned cpx = gridDim.x >> 3;
  const unsigned logical = (bid & 7) * cpx + (bid >> 3);
  const int per_z = nx * ny;
  const int z = (int)(logical / per_z);
  const int rem = (int)(logical - (unsigned)z * per_z);
  const int by = rem / nx;
  const int bx = rem - by * nx;
  const int m0 = by * 128;
  const int n0 = bx * 128;
  if (SKIPN && n0 > m0 + 127) return;  // uniform per block: safe early-out
  A += (long)z * sA;
  B += (long)z * sB;
  C += (long)z * sC;

  __shared__ unsigned short As[128 * 64];
  __shared__ unsigned short Bs[128 * 64];
  char* const AsB = (char*)As;
  char* const BsB = (char*)Bs;

  const int t = threadIdx.x;
  const int l = t & 63;
  const int w = t >> 6;
  const int wr = (w >> 1) * 64;  // wave row base in tile
  const int wc = (w & 1) * 64;   // wave col base in tile

  // Staging map: LDS byte o = i*4096 + t*16 -> row = i*32 + t/8, phys chunk = t&7.
  // Logical chunk c = phys ^ (row&7) = (t&7) ^ ((t>>3)&7).
  const int srow = t >> 3;
  const int sch = (t & 7) ^ (srow & 7);
  const unsigned short* Ag = A + (long)(m0 + srow) * K + sch * 8;
  const unsigned short* Bg = B + (long)(n0 + srow) * K + sch * 8;
  const int soff = t * 16;

  const int ar = wr + (l & 15);   // A-frag row (within tile)
  const int brr = wc + (l & 15);  // B-frag row
  const int kc = l >> 4;          // k-chunk within 32-k step

  f32x4 acc[4][4];
#pragma unroll
  for (int i = 0; i < 4; ++i)
#pragma unroll
    for (int j = 0; j < 4; ++j) acc[i][j] = f32x4{0.f, 0.f, 0.f, 0.f};

  int KT = K >> 6;
  if (LIMK) {
    int kt2 = (m0 + 128) >> 6;
    KT = KT < kt2 ? KT : kt2;
  }

  for (int kt = 0; kt < KT; ++kt) {
    const long ko = (long)kt * 64;
#pragma unroll
    for (int i = 0; i < 4; ++i) GLDS16(Ag + (long)i * 32 * K + ko, AsB + i * 4096 + soff);
#pragma unroll
    for (int i = 0; i < 4; ++i) GLDS16(Bg + (long)i * 32 * K + ko, BsB + i * 4096 + soff);
    __syncthreads();  // compiler emits s_waitcnt vmcnt(0) before s_barrier
#pragma unroll
    for (int kk = 0; kk < 2; ++kk) {
      bf16x8 av[4], bv[4];
#pragma unroll
      for (int m = 0; m < 4; ++m) {
        int r = ar + m * 16;
        int c = (kk * 4 + kc) ^ (r & 7);
        av[m] = *(const bf16x8*)(AsB + r * 128 + c * 16);
      }
#pragma unroll
      for (int n = 0; n < 4; ++n) {
        int r = brr + n * 16;
        int c = (kk * 4 + kc) ^ (r & 7);
        bv[n] = *(const bf16x8*)(BsB + r * 128 + c * 16);
      }
#pragma unroll
      for (int m = 0; m < 4; ++m)
#pragma unroll
        for (int n = 0; n < 4; ++n)
          acc[m][n] = __builtin_amdgcn_mfma_f32_16x16x32_bf16(av[m], bv[n], acc[m][n], 0, 0, 0);
    }
    __syncthreads();
  }

  // C/D layout (m89-verified): col = lane&15, row = (lane>>4)*4 + reg
  const int rb = m0 + wr + (l >> 4) * 4;
  const int cb = n0 + wc + (l & 15);
#pragma unroll
  for (int m = 0; m < 4; ++m)
#pragma unroll
    for (int n = 0; n < 4; ++n)
#pragma unroll
      for (int i = 0; i < 4; ++i) {
        float v = acc[m][n][i] * alpha;
        long off = (long)(rb + m * 16 + i) * N + (cb + n * 16);
        if constexpr (sizeof(CT) == 2)
          C[off] = f2bf(v);
        else
          C[off] = v;
      }
}

// ---------------- causal row softmax, in-place on bf16 P --------------------
// One WAVE per row (4 rows/block); strided fully-coalesced uint4 loads; pure
// shuffle reductions. Writes ALL 2048 cols (zeros beyond diagonal — buffer was
// poisoned and upper score blocks were never written).
__global__ __launch_bounds__(256) void k_softmax(unsigned short* __restrict__ P, int S) {
  const int t = threadIdx.x;
  const int wv = t >> 6, l = t & 63;
  const int q = blockIdx.x * 4 + wv;  // row index
  unsigned short* row = P + ((long)blockIdx.y * S + q) * S;

  // load 32 elems/lane: chunk j covers cols j*512 + l*8 .. +7 (lane-contiguous)
  uint4 raw[4];
#pragma unroll
  for (int j = 0; j < 4; ++j) raw[j] = ((const uint4*)row)[j * 64 + l];
  float v[32];
#pragma unroll
  for (int j = 0; j < 4; ++j) {
    unsigned int rw[4] = {raw[j].x, raw[j].y, raw[j].z, raw[j].w};
#pragma unroll
    for (int e = 0; e < 8; ++e)
      v[j * 8 + e] = bf2f((unsigned short)((rw[e >> 1] >> ((e & 1) * 16)) & 0xFFFF));
  }

  float mx = -3.0e38f;
#pragma unroll
  for (int j = 0; j < 4; ++j)
#pragma unroll
    for (int e = 0; e < 8; ++e) {
      int col = j * 512 + l * 8 + e;
      if (col <= q) mx = fmaxf(mx, v[j * 8 + e]);
    }
#pragma unroll
  for (int o = 32; o >= 1; o >>= 1) mx = fmaxf(mx, __shfl_xor(mx, o, 64));

  float s = 0.f;
#pragma unroll
  for (int j = 0; j < 4; ++j)
#pragma unroll
    for (int e = 0; e < 8; ++e) {
      int col = j * 512 + l * 8 + e;
      float ev = (col <= q) ? __expf(v[j * 8 + e] - mx) : 0.f;
      v[j * 8 + e] = ev;
      s += ev;
    }
#pragma unroll
  for (int o = 32; o >= 1; o >>= 1) s += __shfl_xor(s, o, 64);
  const float inv = 1.f / s;

#pragma unroll
  for (int j = 0; j < 4; ++j) {
    uint4 ow;
    unsigned int o2[4];
#pragma unroll
    for (int jj = 0; jj < 4; ++jj)
      o2[jj] = (unsigned)f2bf(v[j * 8 + 2 * jj] * inv) |
               ((unsigned)f2bf(v[j * 8 + 2 * jj + 1] * inv) << 16);
    ow.x = o2[0]; ow.y = o2[1]; ow.z = o2[2]; ow.w = o2[3];
    ((uint4*)row)[j * 64 + l] = ow;
  }
}

// ---------------------------------------------------------------------------
extern "C" void kernel_launch(void* const* d_in, const int* in_sizes, int n_in, void* d_out,
                              int out_size, void* d_ws, size_t ws_size, hipStream_t stream) {
  const int B = 4, S = 2048, D = 1024;
  const long MS = (long)B * S;  // 8192 flattened tokens

  const float* x = (const float*)d_in[0];
  const float* Wq = (const float*)d_in[1];
  const float* Wk = (const float*)d_in[2];
  const float* Wv = (const float*)d_in[3];
  float* out = (float*)d_out;

  // workspace layout (ushort elements)
  unsigned short* xb = (unsigned short*)d_ws;   // [8192][1024]
  unsigned short* Wt = xb + MS * D;             // 3 x [1024][1024] (transposed)
  unsigned short* Qb = Wt + 3L * D * D;         // [8192][1024]
  unsigned short* Kb = Qb + MS * D;             // [8192][1024]
  unsigned short* Vt = Kb + MS * D;             // 4 x [1024][2048]  (V^T directly)
  unsigned short* P  = Vt + MS * D;             // 4 x [2048][2048] scores->probs
  (void)ws_size;

  // 1) x -> bf16
  long n = MS * D;
  k_cvt<<<dim3((unsigned)(n / 8 / 256)), 256, 0, stream>>>(x, xb, n);
  // 2) W -> bf16 transposed [n][k]
  k_trans_w<<<dim3(32, 32, 3), dim3(32, 8), 0, stream>>>(Wq, Wk, Wv, Wt, D);
  // 3) Q,K projections: {Q,K}b = xb @ Wt^T   (z in {0,1}; nwg = 8*64*2 = 1024)
  k_gemm_bt<unsigned short, false, false><<<1024, 256, 0, stream>>>(
      xb, Wt, Qb, /*nx=*/D / 128, /*ny=*/(int)(MS / 128), /*N=*/D, /*K=*/D,
      /*sA=*/0L, /*sB=*/(long)D * D, /*sC=*/MS * D, 1.0f);
  // 4) V^T directly: Vt[f][s] = sum_k Wv^T[f][k] * xb_b[s][k]   (nwg = 16*8*4 = 512)
  k_gemm_bt<unsigned short, false, false><<<512, 256, 0, stream>>>(
      Wt + 2L * D * D, xb, Vt, /*nx=*/S / 128, /*ny=*/D / 128, /*N=*/S, /*K=*/D,
      /*sA=*/0L, /*sB=*/(long)S * D, /*sC=*/(long)D * S, 1.0f);
  // 5) scores: P = (Q @ K^T) / 32, skipping fully-masked blocks (nwg = 16*16*4 = 1024)
  k_gemm_bt<unsigned short, true, false><<<1024, 256, 0, stream>>>(
      Qb, Kb, P, /*nx=*/S / 128, /*ny=*/S / 128, /*N=*/S, /*K=*/D,
      /*sA=*/(long)S * D, /*sB=*/(long)S * D, /*sC=*/(long)S * S, 0.03125f);
  // 6) causal softmax rows (writes zeros above diagonal)
  k_softmax<<<dim3(S / 4, B), 256, 0, stream>>>(P, S);
  // 7) out = P @ V  (K-tiles clamped at the diagonal; nwg = 8*16*4 = 512)
  k_gemm_bt<float, false, true><<<512, 256, 0, stream>>>(
      P, Vt, out, /*nx=*/D / 128, /*ny=*/S / 128, /*N=*/D, /*K=*/S,
      /*sA=*/(long)S * S, /*sB=*/(long)D * S, /*sC=*/(long)S * D, 1.0f);
}

// Round 4
// 163.768 us; speedup vs baseline: 1.1667x; 1.0792x over previous
//
#include <hip/hip_runtime.h>

// ---------------------------------------------------------------------------
// CausalAttention: out = softmax(mask(QK^T/sqrt(D))) @ V,  Q/K/V = x @ W_{q,k,v}
// B=4, S=2048, D_IN=D_OUT=1024, fp32 in/out, bf16 MFMA internally.
// R3: triangular block launch for scores (no dead blocks) + complementary
// row-pair ordering for PV — fixes the 2.8x per-XCD work imbalance the R2
// chunked swizzle created on causally-shaped work (MfmaUtil 13% -> ~27%).
// ---------------------------------------------------------------------------

typedef __bf16 bf16x8 __attribute__((ext_vector_type(8)));
typedef float f32x4 __attribute__((ext_vector_type(4)));

__device__ __forceinline__ unsigned short f2bf(float f) {
  unsigned int u = __builtin_bit_cast(unsigned int, f);
  u += 0x7FFFu + ((u >> 16) & 1u);  // RNE
  return (unsigned short)(u >> 16);
}
__device__ __forceinline__ float bf2f(unsigned short h) {
  unsigned int u = ((unsigned int)h) << 16;
  return __builtin_bit_cast(float, u);
}

#define GLDS16(g, l)                                                                   \
  __builtin_amdgcn_global_load_lds((const __attribute__((address_space(1))) void*)(g), \
                                   (__attribute__((address_space(3))) void*)(l), 16, 0, 0)

// ---------------- fp32 -> bf16 convert (8 elems/lane) ----------------
__global__ __launch_bounds__(256) void k_cvt(const float* __restrict__ in,
                                             unsigned short* __restrict__ out, long n) {
  long i = ((long)blockIdx.x * 256 + threadIdx.x) * 8;
  if (i >= n) return;  // n is a multiple of 8
  float4 a = *(const float4*)(in + i);
  float4 b = *(const float4*)(in + i + 4);
  uint4 o;
  o.x = (unsigned)f2bf(a.x) | ((unsigned)f2bf(a.y) << 16);
  o.y = (unsigned)f2bf(a.z) | ((unsigned)f2bf(a.w) << 16);
  o.z = (unsigned)f2bf(b.x) | ((unsigned)f2bf(b.y) << 16);
  o.w = (unsigned)f2bf(b.z) | ((unsigned)f2bf(b.w) << 16);
  *(uint4*)(out + i) = o;
}

// ---------------- W[k][n] fp32 -> Wt[n][k] bf16 (3 weights via grid.z) ------
__global__ void k_trans_w(const float* __restrict__ W0, const float* __restrict__ W1,
                          const float* __restrict__ W2, unsigned short* __restrict__ Wt, int D) {
  const float* W = blockIdx.z == 0 ? W0 : (blockIdx.z == 1 ? W1 : W2);
  unsigned short* out = Wt + (long)blockIdx.z * D * D;
  __shared__ float tile[32][33];
  int tx = threadIdx.x, ty = threadIdx.y;  // (32,8)
  int bx = blockIdx.x * 32, by = blockIdx.y * 32;
#pragma unroll
  for (int j = 0; j < 4; ++j) tile[ty + j * 8][tx] = W[(long)(by + ty + j * 8) * D + bx + tx];
  __syncthreads();
#pragma unroll
  for (int j = 0; j < 4; ++j)
    out[(long)(bx + ty + j * 8) * D + by + tx] = f2bf(tile[tx][ty + j * 8]);
}

// ---------------- BT GEMM: C[m][n] = alpha * sum_k A[m][k] * B[n][k] --------
// m97 structure: 128x128 tile, BK=64, 4 waves (2x2, 64x64 each), 16x16x32 MFMA,
// global_load_lds width 16, source-side XOR chunk-swizzle (LDS linear),
// SQ_LDS_BANK_CONFLICT == 0 (measured).
// 1-D grid, bijective XCD-chunk swizzle (gridDim.x % 8 == 0 at all call sites).
// MODE 0: dense row-major (by,bx) decode (proj, V^T GEMMs).
// MODE 1: triangular decode — grid covers ONLY live causal blocks (bx<=by),
//         per_z = ny*(ny+1)/2. Equal work per block -> balanced XCD chunks.
// MODE 2: complementary row-pair order (j -> by: 0,ny-1,1,ny-2,...) + K-tiles
//         clamped at the causal diagonal. Each XCD chunk holds matched
//         short+long rows -> equal K-work per XCD.
template <typename CT, int MODE>
__global__ __launch_bounds__(256) void k_gemm_bt(const unsigned short* __restrict__ A,
                                                 const unsigned short* __restrict__ B,
                                                 CT* __restrict__ C, int nx, int ny, int N, int K,
                                                 long sA, long sB, long sC, float alpha) {
  const unsigned bid = blockIdx.x;
  const unsigned cpx = gridDim.x >> 3;
  const unsigned logical = (bid & 7) * cpx + (bid >> 3);
  int z, by, bx;
  if constexpr (MODE == 1) {
    const int per_z = ny * (ny + 1) / 2;
    z = (int)(logical / per_z);
    int r = (int)(logical - (unsigned)z * per_z);
    int b = (int)((sqrtf(8.f * (float)r + 1.f) - 1.f) * 0.5f);
    while ((b + 1) * (b + 2) / 2 <= r) ++b;  // fixup (fp edge)
    while (b * (b + 1) / 2 > r) --b;
    by = b;
    bx = r - b * (b + 1) / 2;
  } else {
    const int per_z = nx * ny;
    z = (int)(logical / per_z);
    int r = (int)(logical - (unsigned)z * per_z);
    int j = r / nx;
    bx = r - j * nx;
    by = (MODE == 2) ? ((j & 1) ? (ny - 1 - (j >> 1)) : (j >> 1)) : j;
  }
  const int m0 = by * 128;
  const int n0 = bx * 128;
  A += (long)z * sA;
  B += (long)z * sB;
  C += (long)z * sC;

  __shared__ unsigned short As[128 * 64];
  __shared__ unsigned short Bs[128 * 64];
  char* const AsB = (char*)As;
  char* const BsB = (char*)Bs;

  const int t = threadIdx.x;
  const int l = t & 63;
  const int w = t >> 6;
  const int wr = (w >> 1) * 64;  // wave row base in tile
  const int wc = (w & 1) * 64;   // wave col base in tile

  // Staging map: LDS byte o = i*4096 + t*16 -> row = i*32 + t/8, phys chunk = t&7.
  // Logical chunk c = phys ^ (row&7) = (t&7) ^ ((t>>3)&7).
  const int srow = t >> 3;
  const int sch = (t & 7) ^ (srow & 7);
  const unsigned short* Ag = A + (long)(m0 + srow) * K + sch * 8;
  const unsigned short* Bg = B + (long)(n0 + srow) * K + sch * 8;
  const int soff = t * 16;

  const int ar = wr + (l & 15);   // A-frag row (within tile)
  const int brr = wc + (l & 15);  // B-frag row
  const int kc = l >> 4;          // k-chunk within 32-k step

  f32x4 acc[4][4];
#pragma unroll
  for (int i = 0; i < 4; ++i)
#pragma unroll
    for (int j = 0; j < 4; ++j) acc[i][j] = f32x4{0.f, 0.f, 0.f, 0.f};

  int KT = K >> 6;
  if (MODE == 2) {
    int kt2 = (m0 + 128) >> 6;
    KT = KT < kt2 ? KT : kt2;
  }

  for (int kt = 0; kt < KT; ++kt) {
    const long ko = (long)kt * 64;
#pragma unroll
    for (int i = 0; i < 4; ++i) GLDS16(Ag + (long)i * 32 * K + ko, AsB + i * 4096 + soff);
#pragma unroll
    for (int i = 0; i < 4; ++i) GLDS16(Bg + (long)i * 32 * K + ko, BsB + i * 4096 + soff);
    __syncthreads();  // compiler emits s_waitcnt vmcnt(0) before s_barrier
#pragma unroll
    for (int kk = 0; kk < 2; ++kk) {
      bf16x8 av[4], bv[4];
#pragma unroll
      for (int m = 0; m < 4; ++m) {
        int r = ar + m * 16;
        int c = (kk * 4 + kc) ^ (r & 7);
        av[m] = *(const bf16x8*)(AsB + r * 128 + c * 16);
      }
#pragma unroll
      for (int n = 0; n < 4; ++n) {
        int r = brr + n * 16;
        int c = (kk * 4 + kc) ^ (r & 7);
        bv[n] = *(const bf16x8*)(BsB + r * 128 + c * 16);
      }
#pragma unroll
      for (int m = 0; m < 4; ++m)
#pragma unroll
        for (int n = 0; n < 4; ++n)
          acc[m][n] = __builtin_amdgcn_mfma_f32_16x16x32_bf16(av[m], bv[n], acc[m][n], 0, 0, 0);
    }
    __syncthreads();
  }

  // C/D layout (m89-verified): col = lane&15, row = (lane>>4)*4 + reg
  const int rb = m0 + wr + (l >> 4) * 4;
  const int cb = n0 + wc + (l & 15);
#pragma unroll
  for (int m = 0; m < 4; ++m)
#pragma unroll
    for (int n = 0; n < 4; ++n)
#pragma unroll
      for (int i = 0; i < 4; ++i) {
        float v = acc[m][n][i] * alpha;
        long off = (long)(rb + m * 16 + i) * N + (cb + n * 16);
        if constexpr (sizeof(CT) == 2)
          C[off] = f2bf(v);
        else
          C[off] = v;
      }
}

// ---------------- causal row softmax, in-place on bf16 P --------------------
// One WAVE per row (4 rows/block); strided fully-coalesced uint4 loads; pure
// shuffle reductions. Writes ALL 2048 cols (zeros beyond diagonal — buffer was
// poisoned and upper score blocks were never written).
__global__ __launch_bounds__(256) void k_softmax(unsigned short* __restrict__ P, int S) {
  const int t = threadIdx.x;
  const int wv = t >> 6, l = t & 63;
  const int q = blockIdx.x * 4 + wv;  // row index
  unsigned short* row = P + ((long)blockIdx.y * S + q) * S;

  uint4 raw[4];
#pragma unroll
  for (int j = 0; j < 4; ++j) raw[j] = ((const uint4*)row)[j * 64 + l];
  float v[32];
#pragma unroll
  for (int j = 0; j < 4; ++j) {
    unsigned int rw[4] = {raw[j].x, raw[j].y, raw[j].z, raw[j].w};
#pragma unroll
    for (int e = 0; e < 8; ++e)
      v[j * 8 + e] = bf2f((unsigned short)((rw[e >> 1] >> ((e & 1) * 16)) & 0xFFFF));
  }

  float mx = -3.0e38f;
#pragma unroll
  for (int j = 0; j < 4; ++j)
#pragma unroll
    for (int e = 0; e < 8; ++e) {
      int col = j * 512 + l * 8 + e;
      if (col <= q) mx = fmaxf(mx, v[j * 8 + e]);
    }
#pragma unroll
  for (int o = 32; o >= 1; o >>= 1) mx = fmaxf(mx, __shfl_xor(mx, o, 64));

  float s = 0.f;
#pragma unroll
  for (int j = 0; j < 4; ++j)
#pragma unroll
    for (int e = 0; e < 8; ++e) {
      int col = j * 512 + l * 8 + e;
      float ev = (col <= q) ? __expf(v[j * 8 + e] - mx) : 0.f;
      v[j * 8 + e] = ev;
      s += ev;
    }
#pragma unroll
  for (int o = 32; o >= 1; o >>= 1) s += __shfl_xor(s, o, 64);
  const float inv = 1.f / s;

#pragma unroll
  for (int j = 0; j < 4; ++j) {
    uint4 ow;
    unsigned int o2[4];
#pragma unroll
    for (int jj = 0; jj < 4; ++jj)
      o2[jj] = (unsigned)f2bf(v[j * 8 + 2 * jj] * inv) |
               ((unsigned)f2bf(v[j * 8 + 2 * jj + 1] * inv) << 16);
    ow.x = o2[0]; ow.y = o2[1]; ow.z = o2[2]; ow.w = o2[3];
    ((uint4*)row)[j * 64 + l] = ow;
  }
}

// ---------------------------------------------------------------------------
extern "C" void kernel_launch(void* const* d_in, const int* in_sizes, int n_in, void* d_out,
                              int out_size, void* d_ws, size_t ws_size, hipStream_t stream) {
  const int B = 4, S = 2048, D = 1024;
  const long MS = (long)B * S;  // 8192 flattened tokens

  const float* x = (const float*)d_in[0];
  const float* Wq = (const float*)d_in[1];
  const float* Wk = (const float*)d_in[2];
  const float* Wv = (const float*)d_in[3];
  float* out = (float*)d_out;

  // workspace layout (ushort elements)
  unsigned short* xb = (unsigned short*)d_ws;   // [8192][1024]
  unsigned short* Wt = xb + MS * D;             // 3 x [1024][1024] (transposed)
  unsigned short* Qb = Wt + 3L * D * D;         // [8192][1024]
  unsigned short* Kb = Qb + MS * D;             // [8192][1024]
  unsigned short* Vt = Kb + MS * D;             // 4 x [1024][2048]  (V^T directly)
  unsigned short* P  = Vt + MS * D;             // 4 x [2048][2048] scores->probs
  (void)ws_size;

  // 1) x -> bf16
  long n = MS * D;
  k_cvt<<<dim3((unsigned)(n / 8 / 256)), 256, 0, stream>>>(x, xb, n);
  // 2) W -> bf16 transposed [n][k]
  k_trans_w<<<dim3(32, 32, 3), dim3(32, 8), 0, stream>>>(Wq, Wk, Wv, Wt, D);
  // 3) Q,K projections: {Q,K}b = xb @ Wt^T   (z in {0,1}; nwg = 8*64*2 = 1024)
  k_gemm_bt<unsigned short, 0><<<1024, 256, 0, stream>>>(
      xb, Wt, Qb, /*nx=*/D / 128, /*ny=*/(int)(MS / 128), /*N=*/D, /*K=*/D,
      /*sA=*/0L, /*sB=*/(long)D * D, /*sC=*/MS * D, 1.0f);
  // 4) V^T directly: Vt[f][s] = sum_k Wv^T[f][k] * xb_b[s][k]   (nwg = 16*8*4 = 512)
  k_gemm_bt<unsigned short, 0><<<512, 256, 0, stream>>>(
      Wt + 2L * D * D, xb, Vt, /*nx=*/S / 128, /*ny=*/D / 128, /*N=*/S, /*K=*/D,
      /*sA=*/0L, /*sB=*/(long)S * D, /*sC=*/(long)D * S, 1.0f);
  // 5) scores: P = (Q @ K^T) / 32 — triangular launch, live blocks only
  //    (nwg = 4 * 16*17/2 = 544; 544 % 8 == 0)
  k_gemm_bt<unsigned short, 1><<<544, 256, 0, stream>>>(
      Qb, Kb, P, /*nx=*/S / 128, /*ny=*/S / 128, /*N=*/S, /*K=*/D,
      /*sA=*/(long)S * D, /*sB=*/(long)S * D, /*sC=*/(long)S * S, 0.03125f);
  // 6) causal softmax rows (writes zeros above diagonal)
  k_softmax<<<dim3(S / 4, B), 256, 0, stream>>>(P, S);
  // 7) out = P @ V — K clamped at diagonal, complementary row-pair order
  //    (nwg = 8*16*4 = 512)
  k_gemm_bt<float, 2><<<512, 256, 0, stream>>>(
      P, Vt, out, /*nx=*/D / 128, /*ny=*/S / 128, /*N=*/D, /*K=*/S,
      /*sA=*/(long)S * S, /*sB=*/(long)D * S, /*sC=*/(long)S * D, 1.0f);
}

// Round 5
// 153.451 us; speedup vs baseline: 1.2451x; 1.0672x over previous
//
#include <hip/hip_runtime.h>

// ---------------------------------------------------------------------------
// CausalAttention: out = softmax(mask(QK^T/sqrt(D))) @ V,  Q/K/V = x @ W_{q,k,v}
// B=4, S=2048, D_IN=D_OUT=1024, fp32 in/out, bf16 MFMA internally.
// R4: projection GEMM ported to the 256^2 8-phase schedule (T2+T3+T4+T5,
// counted vmcnt(6), setprio around MFMA clusters); live-region softmax.
// Scores/PV/Vt stay on the balanced 128^2 m97 core (CU-count limited shapes).
// ---------------------------------------------------------------------------

typedef __bf16 bf16x8 __attribute__((ext_vector_type(8)));
typedef float f32x4 __attribute__((ext_vector_type(4)));

__device__ __forceinline__ unsigned short f2bf(float f) {
  unsigned int u = __builtin_bit_cast(unsigned int, f);
  u += 0x7FFFu + ((u >> 16) & 1u);  // RNE
  return (unsigned short)(u >> 16);
}
__device__ __forceinline__ float bf2f(unsigned short h) {
  unsigned int u = ((unsigned int)h) << 16;
  return __builtin_bit_cast(float, u);
}

#define GLDS16(g, l)                                                                   \
  __builtin_amdgcn_global_load_lds((const __attribute__((address_space(1))) void*)(g), \
                                   (__attribute__((address_space(3))) void*)(l), 16, 0, 0)

// ---------------- fp32 -> bf16 convert (8 elems/lane) ----------------
__global__ __launch_bounds__(256) void k_cvt(const float* __restrict__ in,
                                             unsigned short* __restrict__ out, long n) {
  long i = ((long)blockIdx.x * 256 + threadIdx.x) * 8;
  if (i >= n) return;
  float4 a = *(const float4*)(in + i);
  float4 b = *(const float4*)(in + i + 4);
  uint4 o;
  o.x = (unsigned)f2bf(a.x) | ((unsigned)f2bf(a.y) << 16);
  o.y = (unsigned)f2bf(a.z) | ((unsigned)f2bf(a.w) << 16);
  o.z = (unsigned)f2bf(b.x) | ((unsigned)f2bf(b.y) << 16);
  o.w = (unsigned)f2bf(b.z) | ((unsigned)f2bf(b.w) << 16);
  *(uint4*)(out + i) = o;
}

// ---------------- W[k][n] fp32 -> Wt[n][k] bf16 (3 weights via grid.z) ------
__global__ void k_trans_w(const float* __restrict__ W0, const float* __restrict__ W1,
                          const float* __restrict__ W2, unsigned short* __restrict__ Wt, int D) {
  const float* W = blockIdx.z == 0 ? W0 : (blockIdx.z == 1 ? W1 : W2);
  unsigned short* out = Wt + (long)blockIdx.z * D * D;
  __shared__ float tile[32][33];
  int tx = threadIdx.x, ty = threadIdx.y;  // (32,8)
  int bx = blockIdx.x * 32, by = blockIdx.y * 32;
#pragma unroll
  for (int j = 0; j < 4; ++j) tile[ty + j * 8][tx] = W[(long)(by + ty + j * 8) * D + bx + tx];
  __syncthreads();
#pragma unroll
  for (int j = 0; j < 4; ++j)
    out[(long)(bx + ty + j * 8) * D + by + tx] = f2bf(tile[tx][ty + j * 8]);
}

// ======================= 256^2 8-phase BT GEMM ==============================
// BM=BN=256, BK=64, 8 waves (2M x 4N), per-wave C = 128x64. LDS 128 KiB:
// A[buf][half][128 rows][64 k] bf16 at byte buf*32768+half*16384, B at +65536.
// Same source-side XOR chunk swizzle as the 128^2 core (0 bank conflicts).
// Schedule (per iter = 2 K-tiles, tiles 2j->buf0, 2j+1->buf1):
//   P1 rd(A mh0,B nh0|b0) stg(b1.Ah1,t=2j+1)  MFMA(0,0)
//   P2 rd(B nh1|b0)                           MFMA(0,1)
//   P3 rd(A mh1|b0)      stg(b0.Bh0,t=2j+2)   MFMA(1,1)
//   P4                   stg(b0.Ah0,b0.Bh1) vmcnt(6)  MFMA(1,0)
//   P5 rd(A mh0,B nh0|b1) stg(b0.Ah1)         MFMA(0,0)
//   P6 rd(B nh1|b1)                           MFMA(0,1)
//   P7 rd(A mh1|b1)      stg(b1.Bh0,t=2j+3)   MFMA(1,1)
//   P8                   stg(b1.Bh1,b1.Ah0) vmcnt(6)  MFMA(1,0)
// Prologue: tile0 (4 halves) + tile1 (Bh0,Bh1,Ah0), vmcnt(6), barrier.
// Final iter: only P1's stage; vmcnt(0) at P4.
template <typename CT>
__global__ __launch_bounds__(512, 2) void k_gemm256(const unsigned short* __restrict__ A,
                                                    const unsigned short* __restrict__ B,
                                                    CT* __restrict__ C, int nx, int ny, int N,
                                                    int K, long sA, long sB, long sC,
                                                    float alpha) {
  const unsigned bid = blockIdx.x;
  const unsigned cpx = gridDim.x >> 3;
  const unsigned logical = (bid & 7) * cpx + (bid >> 3);
  const int per_z = nx * ny;
  const int z = (int)(logical / per_z);
  const int rem = (int)(logical - (unsigned)z * per_z);
  const int by = rem / nx;
  const int bx = rem - by * nx;
  const int m0 = by * 256, n0 = bx * 256;
  A += (long)z * sA;
  B += (long)z * sB;
  C += (long)z * sC;

  __shared__ char lds[131072];

  const int t = threadIdx.x;
  const int l = t & 63;
  const int w = t >> 6;
  const int wm = w >> 2;  // 0..1
  const int wn = w & 3;   // 0..3

  // staging map (per half-tile: 128 rows x 128 B; 2 x 16 B per thread)
  const int srow = t >> 3;                  // 0..63
  const int sch = (t & 7) ^ (srow & 7);     // source-side swizzle
  const int soff = t * 16;

#define STG(mat, bf, hf, kt)                                                              \
  do {                                                                                    \
    const unsigned short* g =                                                             \
        ((mat) ? B + (long)(n0 + (hf)*128 + srow) * K : A + (long)(m0 + (hf)*128 + srow) * K) + \
        (long)(kt)*64 + sch * 8;                                                          \
    char* d = lds + (mat)*65536 + (bf)*32768 + (hf)*16384 + soff;                         \
    GLDS16(g, d);                                                                         \
    GLDS16(g + (long)64 * K, d + 8192);                                                   \
  } while (0)

  // ds_read bases: lane l reads row (…+(l&15)), k-chunk (kk*4+(l>>4)) ^ (l&7)
  const int lx = l & 15;
  const int kx0 = ((l >> 4) ^ (l & 7)) * 16;
  const int kx1 = ((4 + (l >> 4)) ^ (l & 7)) * 16;
  char* const aB = lds + wm * 16384 + lx * 128;
  char* const bB = lds + 65536 + (wn >> 1) * 16384 + ((wn & 1) * 64 + lx) * 128;

  bf16x8 av[4][2], bv0[2][2], bv1[2][2];
  f32x4 acc[8][4];
#pragma unroll
  for (int i = 0; i < 8; ++i)
#pragma unroll
    for (int jn = 0; jn < 4; ++jn) acc[i][jn] = f32x4{0.f, 0.f, 0.f, 0.f};

#define RDA(bf, mh)                                                     \
  do {                                                                  \
    _Pragma("unroll") for (int m4 = 0; m4 < 4; ++m4) {                  \
      char* p = aB + (bf)*32768 + ((mh)*64 + m4 * 16) * 128;            \
      av[m4][0] = *(const bf16x8*)(p + kx0);                            \
      av[m4][1] = *(const bf16x8*)(p + kx1);                            \
    }                                                                   \
  } while (0)
#define RDB(dst, bf, nh)                                                \
  do {                                                                  \
    _Pragma("unroll") for (int n2 = 0; n2 < 2; ++n2) {                  \
      char* p = bB + (bf)*32768 + (((nh)*2 + n2) * 16) * 128;           \
      dst[n2][0] = *(const bf16x8*)(p + kx0);                           \
      dst[n2][1] = *(const bf16x8*)(p + kx1);                           \
    }                                                                   \
  } while (0)
#define MFM(bv, mh, nh)                                                                    \
  do {                                                                                     \
    __builtin_amdgcn_s_setprio(1);                                                         \
    _Pragma("unroll") for (int m4 = 0; m4 < 4; ++m4) _Pragma("unroll") for (int n2 = 0;    \
                                                                            n2 < 2; ++n2) { \
      acc[(mh)*4 + m4][(nh)*2 + n2] = __builtin_amdgcn_mfma_f32_16x16x32_bf16(             \
          av[m4][0], bv[n2][0], acc[(mh)*4 + m4][(nh)*2 + n2], 0, 0, 0);                   \
      acc[(mh)*4 + m4][(nh)*2 + n2] = __builtin_amdgcn_mfma_f32_16x16x32_bf16(             \
          av[m4][1], bv[n2][1], acc[(mh)*4 + m4][(nh)*2 + n2], 0, 0, 0);                   \
    }                                                                                      \
    __builtin_amdgcn_s_setprio(0);                                                         \
  } while (0)
#define BAR __builtin_amdgcn_s_barrier()
#define VMC(n) asm volatile("s_waitcnt vmcnt(" #n ")" ::: "memory")

  const int KT = K >> 6;    // 64-wide K-tiles (even; K>=128)
  const int NIT = KT >> 1;  // 2 tiles per iteration

  // prologue
  STG(0, 0, 0, 0); STG(0, 0, 1, 0); STG(1, 0, 0, 0); STG(1, 0, 1, 0);  // tile0 -> buf0
  STG(1, 1, 0, 1); STG(1, 1, 1, 1); STG(0, 1, 0, 1);                   // tile1 -> buf1 (3 halves)
  VMC(6);
  BAR;

  for (int j = 0; j < NIT; ++j) {
    const bool full = (j < NIT - 1);
    // P1
    RDA(0, 0); RDB(bv0, 0, 0);
    STG(0, 1, 1, 2 * j + 1);
    BAR; MFM(bv0, 0, 0); BAR;
    // P2
    RDB(bv1, 0, 1);
    BAR; MFM(bv1, 0, 1); BAR;
    // P3
    RDA(0, 1);
    if (full) STG(1, 0, 0, 2 * j + 2);
    BAR; MFM(bv1, 1, 1); BAR;
    // P4
    if (full) {
      STG(0, 0, 0, 2 * j + 2); STG(1, 0, 1, 2 * j + 2);
      VMC(6);
    } else {
      VMC(0);
    }
    BAR; MFM(bv0, 1, 0); BAR;
    // P5
    RDA(1, 0); RDB(bv0, 1, 0);
    if (full) STG(0, 0, 1, 2 * j + 2);
    BAR; MFM(bv0, 0, 0); BAR;
    // P6
    RDB(bv1, 1, 1);
    BAR; MFM(bv1, 0, 1); BAR;
    // P7
    RDA(1, 1);
    if (full) STG(1, 1, 0, 2 * j + 3);
    BAR; MFM(bv1, 1, 1); BAR;
    // P8
    if (full) {
      STG(1, 1, 1, 2 * j + 3); STG(0, 1, 0, 2 * j + 3);
      VMC(6);
    }
    BAR; MFM(bv0, 1, 0); BAR;
  }

  // C/D layout: col = lane&15, row = (lane>>4)*4 + reg
  const int rb = m0 + wm * 128 + (l >> 4) * 4;
  const int cb = n0 + wn * 64 + (l & 15);
#pragma unroll
  for (int m = 0; m < 8; ++m)
#pragma unroll
    for (int n = 0; n < 4; ++n)
#pragma unroll
      for (int i = 0; i < 4; ++i) {
        float v = acc[m][n][i] * alpha;
        long off = (long)(rb + m * 16 + i) * N + (cb + n * 16);
        if constexpr (sizeof(CT) == 2)
          C[off] = f2bf(v);
        else
          C[off] = v;
      }
#undef STG
#undef RDA
#undef RDB
#undef MFM
#undef BAR
#undef VMC
}

// ======================= 128^2 m97 BT GEMM (modes) ==========================
// MODE 0: dense row-major decode. MODE 1: triangular (scores; bx<=by only).
// MODE 2: complementary row-pair order + K clamped at causal diagonal (PV).
template <typename CT, int MODE>
__global__ __launch_bounds__(256) void k_gemm_bt(const unsigned short* __restrict__ A,
                                                 const unsigned short* __restrict__ B,
                                                 CT* __restrict__ C, int nx, int ny, int N, int K,
                                                 long sA, long sB, long sC, float alpha) {
  const unsigned bid = blockIdx.x;
  const unsigned cpx = gridDim.x >> 3;
  const unsigned logical = (bid & 7) * cpx + (bid >> 3);
  int z, by, bx;
  if constexpr (MODE == 1) {
    const int per_z = ny * (ny + 1) / 2;
    z = (int)(logical / per_z);
    int r = (int)(logical - (unsigned)z * per_z);
    int b = (int)((sqrtf(8.f * (float)r + 1.f) - 1.f) * 0.5f);
    while ((b + 1) * (b + 2) / 2 <= r) ++b;
    while (b * (b + 1) / 2 > r) --b;
    by = b;
    bx = r - b * (b + 1) / 2;
  } else {
    const int per_z = nx * ny;
    z = (int)(logical / per_z);
    int r = (int)(logical - (unsigned)z * per_z);
    int j = r / nx;
    bx = r - j * nx;
    by = (MODE == 2) ? ((j & 1) ? (ny - 1 - (j >> 1)) : (j >> 1)) : j;
  }
  const int m0 = by * 128;
  const int n0 = bx * 128;
  A += (long)z * sA;
  B += (long)z * sB;
  C += (long)z * sC;

  __shared__ unsigned short As[128 * 64];
  __shared__ unsigned short Bs[128 * 64];
  char* const AsB = (char*)As;
  char* const BsB = (char*)Bs;

  const int t = threadIdx.x;
  const int l = t & 63;
  const int w = t >> 6;
  const int wr = (w >> 1) * 64;
  const int wc = (w & 1) * 64;

  const int srow = t >> 3;
  const int sch = (t & 7) ^ (srow & 7);
  const unsigned short* Ag = A + (long)(m0 + srow) * K + sch * 8;
  const unsigned short* Bg = B + (long)(n0 + srow) * K + sch * 8;
  const int soff = t * 16;

  const int ar = wr + (l & 15);
  const int brr = wc + (l & 15);
  const int kc = l >> 4;

  f32x4 acc[4][4];
#pragma unroll
  for (int i = 0; i < 4; ++i)
#pragma unroll
    for (int j = 0; j < 4; ++j) acc[i][j] = f32x4{0.f, 0.f, 0.f, 0.f};

  int KT = K >> 6;
  if (MODE == 2) {
    int kt2 = (m0 + 128) >> 6;
    KT = KT < kt2 ? KT : kt2;
  }

  for (int kt = 0; kt < KT; ++kt) {
    const long ko = (long)kt * 64;
#pragma unroll
    for (int i = 0; i < 4; ++i) GLDS16(Ag + (long)i * 32 * K + ko, AsB + i * 4096 + soff);
#pragma unroll
    for (int i = 0; i < 4; ++i) GLDS16(Bg + (long)i * 32 * K + ko, BsB + i * 4096 + soff);
    __syncthreads();
#pragma unroll
    for (int kk = 0; kk < 2; ++kk) {
      bf16x8 av[4], bv[4];
#pragma unroll
      for (int m = 0; m < 4; ++m) {
        int r = ar + m * 16;
        int c = (kk * 4 + kc) ^ (r & 7);
        av[m] = *(const bf16x8*)(AsB + r * 128 + c * 16);
      }
#pragma unroll
      for (int n = 0; n < 4; ++n) {
        int r = brr + n * 16;
        int c = (kk * 4 + kc) ^ (r & 7);
        bv[n] = *(const bf16x8*)(BsB + r * 128 + c * 16);
      }
#pragma unroll
      for (int m = 0; m < 4; ++m)
#pragma unroll
        for (int n = 0; n < 4; ++n)
          acc[m][n] = __builtin_amdgcn_mfma_f32_16x16x32_bf16(av[m], bv[n], acc[m][n], 0, 0, 0);
    }
    __syncthreads();
  }

  const int rb = m0 + wr + (l >> 4) * 4;
  const int cb = n0 + wc + (l & 15);
#pragma unroll
  for (int m = 0; m < 4; ++m)
#pragma unroll
    for (int n = 0; n < 4; ++n)
#pragma unroll
      for (int i = 0; i < 4; ++i) {
        float v = acc[m][n][i] * alpha;
        long off = (long)(rb + m * 16 + i) * N + (cb + n * 16);
        if constexpr (sizeof(CT) == 2)
          C[off] = f2bf(v);
        else
          C[off] = v;
      }
}

// ---------------- causal row softmax, live-region only ----------------------
// One WAVE per row; processes ceil((q+1)/512) chunks of 512 cols. Writes zeros
// in cols (q, nch*512) — covers the diagonal block's upper part that PV reads;
// cols beyond nch*512 are never read by PV (left poisoned, harmless).
__global__ __launch_bounds__(256) void k_softmax(unsigned short* __restrict__ P, int S) {
  const int t = threadIdx.x;
  const int wv = t >> 6, l = t & 63;
  const int q = blockIdx.x * 4 + wv;
  unsigned short* row = P + ((long)blockIdx.y * S + q) * S;
  const int nch = (q >> 9) + 1;  // 512-col chunks to touch

  uint4 raw[4];
  float v[32];
#pragma unroll
  for (int j = 0; j < 4; ++j)
    if (j < nch) raw[j] = ((const uint4*)row)[j * 64 + l];
#pragma unroll
  for (int j = 0; j < 4; ++j) {
    if (j < nch) {
      unsigned int rw[4] = {raw[j].x, raw[j].y, raw[j].z, raw[j].w};
#pragma unroll
      for (int e = 0; e < 8; ++e)
        v[j * 8 + e] = bf2f((unsigned short)((rw[e >> 1] >> ((e & 1) * 16)) & 0xFFFF));
    }
  }

  float mx = -3.0e38f;
#pragma unroll
  for (int j = 0; j < 4; ++j)
    if (j < nch) {
#pragma unroll
      for (int e = 0; e < 8; ++e) {
        int col = j * 512 + l * 8 + e;
        if (col <= q) mx = fmaxf(mx, v[j * 8 + e]);
      }
    }
#pragma unroll
  for (int o = 32; o >= 1; o >>= 1) mx = fmaxf(mx, __shfl_xor(mx, o, 64));

  float s = 0.f;
#pragma unroll
  for (int j = 0; j < 4; ++j)
    if (j < nch) {
#pragma unroll
      for (int e = 0; e < 8; ++e) {
        int col = j * 512 + l * 8 + e;
        float ev = (col <= q) ? __expf(v[j * 8 + e] - mx) : 0.f;
        v[j * 8 + e] = ev;
        s += ev;
      }
    }
#pragma unroll
  for (int o = 32; o >= 1; o >>= 1) s += __shfl_xor(s, o, 64);
  const float inv = 1.f / s;

#pragma unroll
  for (int j = 0; j < 4; ++j)
    if (j < nch) {
      uint4 ow;
      unsigned int o2[4];
#pragma unroll
      for (int jj = 0; jj < 4; ++jj)
        o2[jj] = (unsigned)f2bf(v[j * 8 + 2 * jj] * inv) |
                 ((unsigned)f2bf(v[j * 8 + 2 * jj + 1] * inv) << 16);
      ow.x = o2[0]; ow.y = o2[1]; ow.z = o2[2]; ow.w = o2[3];
      ((uint4*)row)[j * 64 + l] = ow;
    }
}

// ---------------------------------------------------------------------------
extern "C" void kernel_launch(void* const* d_in, const int* in_sizes, int n_in, void* d_out,
                              int out_size, void* d_ws, size_t ws_size, hipStream_t stream) {
  const int B = 4, S = 2048, D = 1024;
  const long MS = (long)B * S;

  const float* x = (const float*)d_in[0];
  const float* Wq = (const float*)d_in[1];
  const float* Wk = (const float*)d_in[2];
  const float* Wv = (const float*)d_in[3];
  float* out = (float*)d_out;

  unsigned short* xb = (unsigned short*)d_ws;   // [8192][1024]
  unsigned short* Wt = xb + MS * D;             // 3 x [1024][1024] (transposed)
  unsigned short* Qb = Wt + 3L * D * D;         // [8192][1024]
  unsigned short* Kb = Qb + MS * D;             // [8192][1024]
  unsigned short* Vt = Kb + MS * D;             // 4 x [1024][2048]
  unsigned short* P  = Vt + MS * D;             // 4 x [2048][2048]
  (void)ws_size;

  long n = MS * D;
  k_cvt<<<dim3((unsigned)(n / 8 / 256)), 256, 0, stream>>>(x, xb, n);
  k_trans_w<<<dim3(32, 32, 3), dim3(32, 8), 0, stream>>>(Wq, Wk, Wv, Wt, D);
  // Q,K projections on the 8-phase 256^2 kernel: nwg = (1024/256)*(8192/256)*2 = 256
  k_gemm256<unsigned short><<<256, 512, 0, stream>>>(
      xb, Wt, Qb, /*nx=*/D / 256, /*ny=*/(int)(MS / 256), /*N=*/D, /*K=*/D,
      /*sA=*/0L, /*sB=*/(long)D * D, /*sC=*/MS * D, 1.0f);
  // V^T direct: Vt[f][s] = sum_k Wv^T[f][k] * xb_b[s][k]   (nwg = 16*8*4 = 512)
  k_gemm_bt<unsigned short, 0><<<512, 256, 0, stream>>>(
      Wt + 2L * D * D, xb, Vt, /*nx=*/S / 128, /*ny=*/D / 128, /*N=*/S, /*K=*/D,
      /*sA=*/0L, /*sB=*/(long)S * D, /*sC=*/(long)D * S, 1.0f);
  // scores: triangular launch (nwg = 4 * 136 = 544)
  k_gemm_bt<unsigned short, 1><<<544, 256, 0, stream>>>(
      Qb, Kb, P, /*nx=*/S / 128, /*ny=*/S / 128, /*N=*/S, /*K=*/D,
      /*sA=*/(long)S * D, /*sB=*/(long)S * D, /*sC=*/(long)S * S, 0.03125f);
  // causal softmax (live region only)
  k_softmax<<<dim3(S / 4, B), 256, 0, stream>>>(P, S);
  // PV: K clamped at diagonal, complementary row-pair order (nwg = 512)
  k_gemm_bt<float, 2><<<512, 256, 0, stream>>>(
      P, Vt, out, /*nx=*/D / 128, /*ny=*/S / 128, /*N=*/D, /*K=*/S,
      /*sA=*/(long)S * S, /*sB=*/(long)D * S, /*sC=*/(long)S * D, 1.0f);
}

// Round 6
// 145.339 us; speedup vs baseline: 1.3146x; 1.0558x over previous
//
#include <hip/hip_runtime.h>

// ---------------------------------------------------------------------------
// CausalAttention: out = softmax(mask(QK^T/sqrt(D))) @ V,  Q/K/V = x @ W_{q,k,v}
// B=4, S=2048, D_IN=D_OUT=1024, fp32 in/out, bf16 MFMA internally.
// R5: uniform per-BLOCK work for the causal GEMMs. All blocks are co-resident
// (grid < residency capacity), so makespan = longest block; R3's per-XCD
// balancing was the wrong level. New k_gemm_bt64 (128x64 tiles):
//   scores: 64-col triangular launch, 1088 equal blocks (16 K-tiles each)
//   PV:     fused row-pairs (by, 15-by) -> 512 equal blocks (34 K-tiles each)
// ---------------------------------------------------------------------------

typedef __bf16 bf16x8 __attribute__((ext_vector_type(8)));
typedef float f32x4 __attribute__((ext_vector_type(4)));

__device__ __forceinline__ unsigned short f2bf(float f) {
  unsigned int u = __builtin_bit_cast(unsigned int, f);
  u += 0x7FFFu + ((u >> 16) & 1u);  // RNE
  return (unsigned short)(u >> 16);
}
__device__ __forceinline__ float bf2f(unsigned short h) {
  unsigned int u = ((unsigned int)h) << 16;
  return __builtin_bit_cast(float, u);
}

#define GLDS16(g, l)                                                                   \
  __builtin_amdgcn_global_load_lds((const __attribute__((address_space(1))) void*)(g), \
                                   (__attribute__((address_space(3))) void*)(l), 16, 0, 0)

// ---------------- fp32 -> bf16 convert (8 elems/lane) ----------------
__global__ __launch_bounds__(256) void k_cvt(const float* __restrict__ in,
                                             unsigned short* __restrict__ out, long n) {
  long i = ((long)blockIdx.x * 256 + threadIdx.x) * 8;
  if (i >= n) return;
  float4 a = *(const float4*)(in + i);
  float4 b = *(const float4*)(in + i + 4);
  uint4 o;
  o.x = (unsigned)f2bf(a.x) | ((unsigned)f2bf(a.y) << 16);
  o.y = (unsigned)f2bf(a.z) | ((unsigned)f2bf(a.w) << 16);
  o.z = (unsigned)f2bf(b.x) | ((unsigned)f2bf(b.y) << 16);
  o.w = (unsigned)f2bf(b.z) | ((unsigned)f2bf(b.w) << 16);
  *(uint4*)(out + i) = o;
}

// ---------------- W[k][n] fp32 -> Wt[n][k] bf16 (3 weights via grid.z) ------
__global__ void k_trans_w(const float* __restrict__ W0, const float* __restrict__ W1,
                          const float* __restrict__ W2, unsigned short* __restrict__ Wt, int D) {
  const float* W = blockIdx.z == 0 ? W0 : (blockIdx.z == 1 ? W1 : W2);
  unsigned short* out = Wt + (long)blockIdx.z * D * D;
  __shared__ float tile[32][33];
  int tx = threadIdx.x, ty = threadIdx.y;  // (32,8)
  int bx = blockIdx.x * 32, by = blockIdx.y * 32;
#pragma unroll
  for (int j = 0; j < 4; ++j) tile[ty + j * 8][tx] = W[(long)(by + ty + j * 8) * D + bx + tx];
  __syncthreads();
#pragma unroll
  for (int j = 0; j < 4; ++j)
    out[(long)(bx + ty + j * 8) * D + by + tx] = f2bf(tile[tx][ty + j * 8]);
}

// ======================= 256^2 8-phase BT GEMM (projections) ================
template <typename CT>
__global__ __launch_bounds__(512, 2) void k_gemm256(const unsigned short* __restrict__ A,
                                                    const unsigned short* __restrict__ B,
                                                    CT* __restrict__ C, int nx, int ny, int N,
                                                    int K, long sA, long sB, long sC,
                                                    float alpha) {
  const unsigned bid = blockIdx.x;
  const unsigned cpx = gridDim.x >> 3;
  const unsigned logical = (bid & 7) * cpx + (bid >> 3);
  const int per_z = nx * ny;
  const int z = (int)(logical / per_z);
  const int rem = (int)(logical - (unsigned)z * per_z);
  const int by = rem / nx;
  const int bx = rem - by * nx;
  const int m0 = by * 256, n0 = bx * 256;
  A += (long)z * sA;
  B += (long)z * sB;
  C += (long)z * sC;

  __shared__ char lds[131072];

  const int t = threadIdx.x;
  const int l = t & 63;
  const int w = t >> 6;
  const int wm = w >> 2;
  const int wn = w & 3;

  const int srow = t >> 3;
  const int sch = (t & 7) ^ (srow & 7);
  const int soff = t * 16;

#define STG(mat, bf, hf, kt)                                                              \
  do {                                                                                    \
    const unsigned short* g =                                                             \
        ((mat) ? B + (long)(n0 + (hf)*128 + srow) * K : A + (long)(m0 + (hf)*128 + srow) * K) + \
        (long)(kt)*64 + sch * 8;                                                          \
    char* d = lds + (mat)*65536 + (bf)*32768 + (hf)*16384 + soff;                         \
    GLDS16(g, d);                                                                         \
    GLDS16(g + (long)64 * K, d + 8192);                                                   \
  } while (0)

  const int lx = l & 15;
  const int kx0 = ((l >> 4) ^ (l & 7)) * 16;
  const int kx1 = ((4 + (l >> 4)) ^ (l & 7)) * 16;
  char* const aB = lds + wm * 16384 + lx * 128;
  char* const bB = lds + 65536 + (wn >> 1) * 16384 + ((wn & 1) * 64 + lx) * 128;

  bf16x8 av[4][2], bv0[2][2], bv1[2][2];
  f32x4 acc[8][4];
#pragma unroll
  for (int i = 0; i < 8; ++i)
#pragma unroll
    for (int jn = 0; jn < 4; ++jn) acc[i][jn] = f32x4{0.f, 0.f, 0.f, 0.f};

#define RDA(bf, mh)                                                     \
  do {                                                                  \
    _Pragma("unroll") for (int m4 = 0; m4 < 4; ++m4) {                  \
      char* p = aB + (bf)*32768 + ((mh)*64 + m4 * 16) * 128;            \
      av[m4][0] = *(const bf16x8*)(p + kx0);                            \
      av[m4][1] = *(const bf16x8*)(p + kx1);                            \
    }                                                                   \
  } while (0)
#define RDB(dst, bf, nh)                                                \
  do {                                                                  \
    _Pragma("unroll") for (int n2 = 0; n2 < 2; ++n2) {                  \
      char* p = bB + (bf)*32768 + (((nh)*2 + n2) * 16) * 128;           \
      dst[n2][0] = *(const bf16x8*)(p + kx0);                           \
      dst[n2][1] = *(const bf16x8*)(p + kx1);                           \
    }                                                                   \
  } while (0)
#define MFM(bv, mh, nh)                                                                    \
  do {                                                                                     \
    __builtin_amdgcn_s_setprio(1);                                                         \
    _Pragma("unroll") for (int m4 = 0; m4 < 4; ++m4) _Pragma("unroll") for (int n2 = 0;    \
                                                                            n2 < 2; ++n2) { \
      acc[(mh)*4 + m4][(nh)*2 + n2] = __builtin_amdgcn_mfma_f32_16x16x32_bf16(             \
          av[m4][0], bv[n2][0], acc[(mh)*4 + m4][(nh)*2 + n2], 0, 0, 0);                   \
      acc[(mh)*4 + m4][(nh)*2 + n2] = __builtin_amdgcn_mfma_f32_16x16x32_bf16(             \
          av[m4][1], bv[n2][1], acc[(mh)*4 + m4][(nh)*2 + n2], 0, 0, 0);                   \
    }                                                                                      \
    __builtin_amdgcn_s_setprio(0);                                                         \
  } while (0)
#define BAR __builtin_amdgcn_s_barrier()
#define VMC(n) asm volatile("s_waitcnt vmcnt(" #n ")" ::: "memory")

  const int KT = K >> 6;
  const int NIT = KT >> 1;

  STG(0, 0, 0, 0); STG(0, 0, 1, 0); STG(1, 0, 0, 0); STG(1, 0, 1, 0);
  STG(1, 1, 0, 1); STG(1, 1, 1, 1); STG(0, 1, 0, 1);
  VMC(6);
  BAR;

  for (int j = 0; j < NIT; ++j) {
    const bool full = (j < NIT - 1);
    RDA(0, 0); RDB(bv0, 0, 0);
    STG(0, 1, 1, 2 * j + 1);
    BAR; MFM(bv0, 0, 0); BAR;
    RDB(bv1, 0, 1);
    BAR; MFM(bv1, 0, 1); BAR;
    RDA(0, 1);
    if (full) STG(1, 0, 0, 2 * j + 2);
    BAR; MFM(bv1, 1, 1); BAR;
    if (full) {
      STG(0, 0, 0, 2 * j + 2); STG(1, 0, 1, 2 * j + 2);
      VMC(6);
    } else {
      VMC(0);
    }
    BAR; MFM(bv0, 1, 0); BAR;
    RDA(1, 0); RDB(bv0, 1, 0);
    if (full) STG(0, 0, 1, 2 * j + 2);
    BAR; MFM(bv0, 0, 0); BAR;
    RDB(bv1, 1, 1);
    BAR; MFM(bv1, 0, 1); BAR;
    RDA(1, 1);
    if (full) STG(1, 1, 0, 2 * j + 3);
    BAR; MFM(bv1, 1, 1); BAR;
    if (full) {
      STG(1, 1, 1, 2 * j + 3); STG(0, 1, 0, 2 * j + 3);
      VMC(6);
    }
    BAR; MFM(bv0, 1, 0); BAR;
  }

  const int rb = m0 + wm * 128 + (l >> 4) * 4;
  const int cb = n0 + wn * 64 + (l & 15);
#pragma unroll
  for (int m = 0; m < 8; ++m)
#pragma unroll
    for (int n = 0; n < 4; ++n)
#pragma unroll
      for (int i = 0; i < 4; ++i) {
        float v = acc[m][n][i] * alpha;
        long off = (long)(rb + m * 16 + i) * N + (cb + n * 16);
        if constexpr (sizeof(CT) == 2)
          C[off] = f2bf(v);
        else
          C[off] = v;
      }
#undef STG
#undef RDA
#undef RDB
#undef MFM
#undef BAR
#undef VMC
}

// ======================= 128^2 m97 BT GEMM (dense, for V^T) =================
template <typename CT>
__global__ __launch_bounds__(256) void k_gemm_bt(const unsigned short* __restrict__ A,
                                                 const unsigned short* __restrict__ B,
                                                 CT* __restrict__ C, int nx, int ny, int N, int K,
                                                 long sA, long sB, long sC, float alpha) {
  const unsigned bid = blockIdx.x;
  const unsigned cpx = gridDim.x >> 3;
  const unsigned logical = (bid & 7) * cpx + (bid >> 3);
  const int per_z = nx * ny;
  const int z = (int)(logical / per_z);
  const int r = (int)(logical - (unsigned)z * per_z);
  const int by = r / nx;
  const int bx = r - by * nx;
  const int m0 = by * 128;
  const int n0 = bx * 128;
  A += (long)z * sA;
  B += (long)z * sB;
  C += (long)z * sC;

  __shared__ unsigned short As[128 * 64];
  __shared__ unsigned short Bs[128 * 64];
  char* const AsB = (char*)As;
  char* const BsB = (char*)Bs;

  const int t = threadIdx.x;
  const int l = t & 63;
  const int w = t >> 6;
  const int wr = (w >> 1) * 64;
  const int wc = (w & 1) * 64;

  const int srow = t >> 3;
  const int sch = (t & 7) ^ (srow & 7);
  const unsigned short* Ag = A + (long)(m0 + srow) * K + sch * 8;
  const unsigned short* Bg = B + (long)(n0 + srow) * K + sch * 8;
  const int soff = t * 16;

  const int ar = wr + (l & 15);
  const int brr = wc + (l & 15);
  const int kc = l >> 4;

  f32x4 acc[4][4];
#pragma unroll
  for (int i = 0; i < 4; ++i)
#pragma unroll
    for (int j = 0; j < 4; ++j) acc[i][j] = f32x4{0.f, 0.f, 0.f, 0.f};

  const int KT = K >> 6;
  for (int kt = 0; kt < KT; ++kt) {
    const long ko = (long)kt * 64;
#pragma unroll
    for (int i = 0; i < 4; ++i) GLDS16(Ag + (long)i * 32 * K + ko, AsB + i * 4096 + soff);
#pragma unroll
    for (int i = 0; i < 4; ++i) GLDS16(Bg + (long)i * 32 * K + ko, BsB + i * 4096 + soff);
    __syncthreads();
#pragma unroll
    for (int kk = 0; kk < 2; ++kk) {
      bf16x8 av[4], bv[4];
#pragma unroll
      for (int m = 0; m < 4; ++m) {
        int rr = ar + m * 16;
        int c = (kk * 4 + kc) ^ (rr & 7);
        av[m] = *(const bf16x8*)(AsB + rr * 128 + c * 16);
      }
#pragma unroll
      for (int n = 0; n < 4; ++n) {
        int rr = brr + n * 16;
        int c = (kk * 4 + kc) ^ (rr & 7);
        bv[n] = *(const bf16x8*)(BsB + rr * 128 + c * 16);
      }
#pragma unroll
      for (int m = 0; m < 4; ++m)
#pragma unroll
        for (int n = 0; n < 4; ++n)
          acc[m][n] = __builtin_amdgcn_mfma_f32_16x16x32_bf16(av[m], bv[n], acc[m][n], 0, 0, 0);
    }
    __syncthreads();
  }

  const int rb = m0 + wr + (l >> 4) * 4;
  const int cb = n0 + wc + (l & 15);
#pragma unroll
  for (int m = 0; m < 4; ++m)
#pragma unroll
    for (int n = 0; n < 4; ++n)
#pragma unroll
      for (int i = 0; i < 4; ++i) {
        float v = acc[m][n][i] * alpha;
        long off = (long)(rb + m * 16 + i) * N + (cb + n * 16);
        if constexpr (sizeof(CT) == 2)
          C[off] = f2bf(v);
        else
          C[off] = v;
      }
}

// ======================= 128x64 BT GEMM, uniform-work modes =================
// BM=128, BN=64, BK=64; LDS 24 KiB; 4 waves 2x2 over (128,64), wave tile 64x32.
// MODE 0 (scores): 64-col triangular decode; per_z = 272 blocks, each K>>6
//   tiles. Every block identical work.
// MODE 1 (PV): fused row-pair (by, 15-by); every block does exactly 34 K-tiles
//   (2(by+1) + (32-2by)); K clamped at the causal diagonal per segment.
template <typename CT, int MODE>
__global__ __launch_bounds__(256) void k_gemm_bt64(const unsigned short* __restrict__ A,
                                                   const unsigned short* __restrict__ B,
                                                   CT* __restrict__ C, int N, int K, long sA,
                                                   long sB, long sC, float alpha) {
  const unsigned bid = blockIdx.x;
  const unsigned cpx = gridDim.x >> 3;
  const unsigned logical = (bid & 7) * cpx + (bid >> 3);
  int z, by, bx;
  if constexpr (MODE == 0) {
    const int per_z = 272;  // sum_{by=0..15} 2(by+1)
    z = (int)(logical / per_z);
    int r = (int)(logical - (unsigned)z * per_z);
    int b = (int)((sqrtf(4.f * (float)r + 1.f) - 1.f) * 0.5f);
    while ((b + 1) * (b + 2) <= r) ++b;  // cum(b) = b*(b+1)
    while (b * (b + 1) > r) --b;
    by = b;
    bx = r - b * (b + 1);  // 0 .. 2by+1  -> n0 <= m0+64 (live)
  } else {
    const int nx = N >> 6;       // 16
    const int per_z = 8 * nx;    // 128
    z = (int)(logical / per_z);
    int r = (int)(logical - (unsigned)z * per_z);
    by = r / nx;                 // pair id 0..7
    bx = r - by * nx;
  }
  A += (long)z * sA;
  B += (long)z * sB;
  C += (long)z * sC;

  __shared__ unsigned short As[128 * 64];
  __shared__ unsigned short Bs[64 * 64];
  char* const AsB = (char*)As;
  char* const BsB = (char*)Bs;

  const int t = threadIdx.x;
  const int l = t & 63;
  const int w = t >> 6;
  const int wr = (w >> 1) * 64;  // wave row base (0/64)
  const int wc = (w & 1) * 32;   // wave col base (0/32)

  const int srow = t >> 3;
  const int sch = (t & 7) ^ (srow & 7);
  const int soff = t * 16;

  const int ar = wr + (l & 15);
  const int brr = wc + (l & 15);
  const int kc = l >> 4;

  const int n0 = bx * 64;
  const unsigned short* Bg = B + (long)(n0 + srow) * K + sch * 8;

  const int nseg = (MODE == 1) ? 2 : 1;
  for (int seg = 0; seg < nseg; ++seg) {
    const int row = (MODE == 1) ? (seg ? (15 - by) : by) : by;
    const int m0 = row * 128;
    const int KT = (MODE == 1) ? ((m0 + 128) >> 6) : (K >> 6);
    const unsigned short* Ag = A + (long)(m0 + srow) * K + sch * 8;

    f32x4 acc[4][2];
#pragma unroll
    for (int i = 0; i < 4; ++i)
#pragma unroll
      for (int j = 0; j < 2; ++j) acc[i][j] = f32x4{0.f, 0.f, 0.f, 0.f};

    for (int kt = 0; kt < KT; ++kt) {
      const long ko = (long)kt * 64;
#pragma unroll
      for (int i = 0; i < 4; ++i) GLDS16(Ag + (long)i * 32 * K + ko, AsB + i * 4096 + soff);
#pragma unroll
      for (int i = 0; i < 2; ++i) GLDS16(Bg + (long)i * 32 * K + ko, BsB + i * 4096 + soff);
      __syncthreads();
#pragma unroll
      for (int kk = 0; kk < 2; ++kk) {
        bf16x8 av[4], bv[2];
#pragma unroll
        for (int m = 0; m < 4; ++m) {
          int rr = ar + m * 16;
          int c = (kk * 4 + kc) ^ (rr & 7);
          av[m] = *(const bf16x8*)(AsB + rr * 128 + c * 16);
        }
#pragma unroll
        for (int n = 0; n < 2; ++n) {
          int rr = brr + n * 16;
          int c = (kk * 4 + kc) ^ (rr & 7);
          bv[n] = *(const bf16x8*)(BsB + rr * 128 + c * 16);
        }
#pragma unroll
        for (int m = 0; m < 4; ++m)
#pragma unroll
          for (int n = 0; n < 2; ++n)
            acc[m][n] = __builtin_amdgcn_mfma_f32_16x16x32_bf16(av[m], bv[n], acc[m][n], 0, 0, 0);
      }
      __syncthreads();
    }

    const int rb = m0 + wr + (l >> 4) * 4;
    const int cb = n0 + wc + (l & 15);
#pragma unroll
    for (int m = 0; m < 4; ++m)
#pragma unroll
      for (int n = 0; n < 2; ++n)
#pragma unroll
        for (int i = 0; i < 4; ++i) {
          float v = acc[m][n][i] * alpha;
          long off = (long)(rb + m * 16 + i) * N + (cb + n * 16);
          if constexpr (sizeof(CT) == 2)
            C[off] = f2bf(v);
          else
            C[off] = v;
        }
  }
}

// ---------------- causal row softmax, live-region only ----------------------
__global__ __launch_bounds__(256) void k_softmax(unsigned short* __restrict__ P, int S) {
  const int t = threadIdx.x;
  const int wv = t >> 6, l = t & 63;
  const int q = blockIdx.x * 4 + wv;
  unsigned short* row = P + ((long)blockIdx.y * S + q) * S;
  const int nch = (q >> 9) + 1;

  uint4 raw[4];
  float v[32];
#pragma unroll
  for (int j = 0; j < 4; ++j)
    if (j < nch) raw[j] = ((const uint4*)row)[j * 64 + l];
#pragma unroll
  for (int j = 0; j < 4; ++j) {
    if (j < nch) {
      unsigned int rw[4] = {raw[j].x, raw[j].y, raw[j].z, raw[j].w};
#pragma unroll
      for (int e = 0; e < 8; ++e)
        v[j * 8 + e] = bf2f((unsigned short)((rw[e >> 1] >> ((e & 1) * 16)) & 0xFFFF));
    }
  }

  float mx = -3.0e38f;
#pragma unroll
  for (int j = 0; j < 4; ++j)
    if (j < nch) {
#pragma unroll
      for (int e = 0; e < 8; ++e) {
        int col = j * 512 + l * 8 + e;
        if (col <= q) mx = fmaxf(mx, v[j * 8 + e]);
      }
    }
#pragma unroll
  for (int o = 32; o >= 1; o >>= 1) mx = fmaxf(mx, __shfl_xor(mx, o, 64));

  float s = 0.f;
#pragma unroll
  for (int j = 0; j < 4; ++j)
    if (j < nch) {
#pragma unroll
      for (int e = 0; e < 8; ++e) {
        int col = j * 512 + l * 8 + e;
        float ev = (col <= q) ? __expf(v[j * 8 + e] - mx) : 0.f;
        v[j * 8 + e] = ev;
        s += ev;
      }
    }
#pragma unroll
  for (int o = 32; o >= 1; o >>= 1) s += __shfl_xor(s, o, 64);
  const float inv = 1.f / s;

#pragma unroll
  for (int j = 0; j < 4; ++j)
    if (j < nch) {
      uint4 ow;
      unsigned int o2[4];
#pragma unroll
      for (int jj = 0; jj < 4; ++jj)
        o2[jj] = (unsigned)f2bf(v[j * 8 + 2 * jj] * inv) |
                 ((unsigned)f2bf(v[j * 8 + 2 * jj + 1] * inv) << 16);
      ow.x = o2[0]; ow.y = o2[1]; ow.z = o2[2]; ow.w = o2[3];
      ((uint4*)row)[j * 64 + l] = ow;
    }
}

// ---------------------------------------------------------------------------
extern "C" void kernel_launch(void* const* d_in, const int* in_sizes, int n_in, void* d_out,
                              int out_size, void* d_ws, size_t ws_size, hipStream_t stream) {
  const int B = 4, S = 2048, D = 1024;
  const long MS = (long)B * S;

  const float* x = (const float*)d_in[0];
  const float* Wq = (const float*)d_in[1];
  const float* Wk = (const float*)d_in[2];
  const float* Wv = (const float*)d_in[3];
  float* out = (float*)d_out;

  unsigned short* xb = (unsigned short*)d_ws;   // [8192][1024]
  unsigned short* Wt = xb + MS * D;             // 3 x [1024][1024] (transposed)
  unsigned short* Qb = Wt + 3L * D * D;         // [8192][1024]
  unsigned short* Kb = Qb + MS * D;             // [8192][1024]
  unsigned short* Vt = Kb + MS * D;             // 4 x [1024][2048]
  unsigned short* P  = Vt + MS * D;             // 4 x [2048][2048]
  (void)ws_size;

  long n = MS * D;
  k_cvt<<<dim3((unsigned)(n / 8 / 256)), 256, 0, stream>>>(x, xb, n);
  k_trans_w<<<dim3(32, 32, 3), dim3(32, 8), 0, stream>>>(Wq, Wk, Wv, Wt, D);
  // Q,K projections (8-phase 256^2): nwg = 4*32*2 = 256
  k_gemm256<unsigned short><<<256, 512, 0, stream>>>(
      xb, Wt, Qb, /*nx=*/D / 256, /*ny=*/(int)(MS / 256), /*N=*/D, /*K=*/D,
      /*sA=*/0L, /*sB=*/(long)D * D, /*sC=*/MS * D, 1.0f);
  // V^T direct: Vt[f][s] = sum_k Wv^T[f][k] * xb_b[s][k]   (nwg = 16*8*4 = 512)
  k_gemm_bt<unsigned short><<<512, 256, 0, stream>>>(
      Wt + 2L * D * D, xb, Vt, /*nx=*/S / 128, /*ny=*/D / 128, /*N=*/S, /*K=*/D,
      /*sA=*/0L, /*sB=*/(long)S * D, /*sC=*/(long)D * S, 1.0f);
  // scores: 64-col triangular, uniform blocks (nwg = 4*272 = 1088)
  k_gemm_bt64<unsigned short, 0><<<1088, 256, 0, stream>>>(
      Qb, Kb, P, /*N=*/S, /*K=*/D,
      /*sA=*/(long)S * D, /*sB=*/(long)S * D, /*sC=*/(long)S * S, 0.03125f);
  // causal softmax (live region only)
  k_softmax<<<dim3(S / 4, B), 256, 0, stream>>>(P, S);
  // PV: fused row-pairs, 34 K-tiles per block uniform (nwg = 4*8*16 = 512)
  k_gemm_bt64<float, 1><<<512, 256, 0, stream>>>(
      P, Vt, out, /*N=*/D, /*K=*/S,
      /*sA=*/(long)S * S, /*sB=*/(long)D * S, /*sC=*/(long)S * D, 1.0f);
}

// Round 7
// 141.907 us; speedup vs baseline: 1.3464x; 1.0242x over previous
//
#include <hip/hip_runtime.h>

// ---------------------------------------------------------------------------
// CausalAttention: out = softmax(mask(QK^T/sqrt(D))) @ V,  Q/K/V = x @ W_{q,k,v}
// B=4, S=2048, D_IN=D_OUT=1024, fp32 in/out, bf16 MFMA internally.
// R7: PV GEMM upgraded to 2-phase double-buffer + counted vmcnt(6) (T3+T4
// minimum) — PV runs at 2 blocks/CU where implicit overlap is too thin;
// scores stays single-buffered (4.25 blocks/CU demand, dbuf is m99/m100-null
// there and would cut occupancy). cvt+trans_w merged into one launch.
// ---------------------------------------------------------------------------

typedef __bf16 bf16x8 __attribute__((ext_vector_type(8)));
typedef float f32x4 __attribute__((ext_vector_type(4)));

__device__ __forceinline__ unsigned short f2bf(float f) {
  unsigned int u = __builtin_bit_cast(unsigned int, f);
  u += 0x7FFFu + ((u >> 16) & 1u);  // RNE
  return (unsigned short)(u >> 16);
}
__device__ __forceinline__ float bf2f(unsigned short h) {
  unsigned int u = ((unsigned int)h) << 16;
  return __builtin_bit_cast(float, u);
}

#define GLDS16(g, l)                                                                   \
  __builtin_amdgcn_global_load_lds((const __attribute__((address_space(1))) void*)(g), \
                                   (__attribute__((address_space(3))) void*)(l), 16, 0, 0)

// ---------------- merged: fp32->bf16 convert (blocks 0..NCVT) + W transpose --
// cvt: 8 elems/lane. trans_w: W[k][n] -> Wt[n][k] bf16, 32x32 tiles.
__global__ __launch_bounds__(256) void k_prep(const float* __restrict__ x,
                                              unsigned short* __restrict__ xb,
                                              const float* __restrict__ W0,
                                              const float* __restrict__ W1,
                                              const float* __restrict__ W2,
                                              unsigned short* __restrict__ Wt, long n, int ncvt,
                                              int D) {
  const int b = blockIdx.x;
  const int t = threadIdx.x;
  if (b < ncvt) {
    long i = ((long)b * 256 + t) * 8;
    if (i >= n) return;
    float4 a = *(const float4*)(x + i);
    float4 c = *(const float4*)(x + i + 4);
    uint4 o;
    o.x = (unsigned)f2bf(a.x) | ((unsigned)f2bf(a.y) << 16);
    o.y = (unsigned)f2bf(a.z) | ((unsigned)f2bf(a.w) << 16);
    o.z = (unsigned)f2bf(c.x) | ((unsigned)f2bf(c.y) << 16);
    o.w = (unsigned)f2bf(c.z) | ((unsigned)f2bf(c.w) << 16);
    *(uint4*)(xb + i) = o;
    return;
  }
  const int id = b - ncvt;          // 0 .. 3*(D/32)^2-1
  const int nt = (D / 32) * (D / 32);
  const int z = id / nt;
  const int rem = id - z * nt;
  const int by = (rem >> 5) * 32, bx = (rem & 31) * 32;
  const float* W = z == 0 ? W0 : (z == 1 ? W1 : W2);
  unsigned short* out = Wt + (long)z * D * D;
  __shared__ float tile[32][33];
  const int tx = t & 31, ty = t >> 5;  // (32,8)
#pragma unroll
  for (int j = 0; j < 4; ++j) tile[ty + j * 8][tx] = W[(long)(by + ty + j * 8) * D + bx + tx];
  __syncthreads();
#pragma unroll
  for (int j = 0; j < 4; ++j)
    out[(long)(bx + ty + j * 8) * D + by + tx] = f2bf(tile[tx][ty + j * 8]);
}

// ======================= 256^2 8-phase BT GEMM (projections) ================
template <typename CT>
__global__ __launch_bounds__(512, 2) void k_gemm256(const unsigned short* __restrict__ A,
                                                    const unsigned short* __restrict__ B,
                                                    CT* __restrict__ C, int nx, int ny, int N,
                                                    int K, long sA, long sB, long sC,
                                                    float alpha) {
  const unsigned bid = blockIdx.x;
  const unsigned cpx = gridDim.x >> 3;
  const unsigned logical = (bid & 7) * cpx + (bid >> 3);
  const int per_z = nx * ny;
  const int z = (int)(logical / per_z);
  const int rem = (int)(logical - (unsigned)z * per_z);
  const int by = rem / nx;
  const int bx = rem - by * nx;
  const int m0 = by * 256, n0 = bx * 256;
  A += (long)z * sA;
  B += (long)z * sB;
  C += (long)z * sC;

  __shared__ char lds[131072];

  const int t = threadIdx.x;
  const int l = t & 63;
  const int w = t >> 6;
  const int wm = w >> 2;
  const int wn = w & 3;

  const int srow = t >> 3;
  const int sch = (t & 7) ^ (srow & 7);
  const int soff = t * 16;

#define STG(mat, bf, hf, kt)                                                              \
  do {                                                                                    \
    const unsigned short* g =                                                             \
        ((mat) ? B + (long)(n0 + (hf)*128 + srow) * K : A + (long)(m0 + (hf)*128 + srow) * K) + \
        (long)(kt)*64 + sch * 8;                                                          \
    char* d = lds + (mat)*65536 + (bf)*32768 + (hf)*16384 + soff;                         \
    GLDS16(g, d);                                                                         \
    GLDS16(g + (long)64 * K, d + 8192);                                                   \
  } while (0)

  const int lx = l & 15;
  const int kx0 = ((l >> 4) ^ (l & 7)) * 16;
  const int kx1 = ((4 + (l >> 4)) ^ (l & 7)) * 16;
  char* const aB = lds + wm * 16384 + lx * 128;
  char* const bB = lds + 65536 + (wn >> 1) * 16384 + ((wn & 1) * 64 + lx) * 128;

  bf16x8 av[4][2], bv0[2][2], bv1[2][2];
  f32x4 acc[8][4];
#pragma unroll
  for (int i = 0; i < 8; ++i)
#pragma unroll
    for (int jn = 0; jn < 4; ++jn) acc[i][jn] = f32x4{0.f, 0.f, 0.f, 0.f};

#define RDA(bf, mh)                                                     \
  do {                                                                  \
    _Pragma("unroll") for (int m4 = 0; m4 < 4; ++m4) {                  \
      char* p = aB + (bf)*32768 + ((mh)*64 + m4 * 16) * 128;            \
      av[m4][0] = *(const bf16x8*)(p + kx0);                            \
      av[m4][1] = *(const bf16x8*)(p + kx1);                            \
    }                                                                   \
  } while (0)
#define RDB(dst, bf, nh)                                                \
  do {                                                                  \
    _Pragma("unroll") for (int n2 = 0; n2 < 2; ++n2) {                  \
      char* p = bB + (bf)*32768 + (((nh)*2 + n2) * 16) * 128;           \
      dst[n2][0] = *(const bf16x8*)(p + kx0);                           \
      dst[n2][1] = *(const bf16x8*)(p + kx1);                           \
    }                                                                   \
  } while (0)
#define MFM(bv, mh, nh)                                                                    \
  do {                                                                                     \
    __builtin_amdgcn_s_setprio(1);                                                         \
    _Pragma("unroll") for (int m4 = 0; m4 < 4; ++m4) _Pragma("unroll") for (int n2 = 0;    \
                                                                            n2 < 2; ++n2) { \
      acc[(mh)*4 + m4][(nh)*2 + n2] = __builtin_amdgcn_mfma_f32_16x16x32_bf16(             \
          av[m4][0], bv[n2][0], acc[(mh)*4 + m4][(nh)*2 + n2], 0, 0, 0);                   \
      acc[(mh)*4 + m4][(nh)*2 + n2] = __builtin_amdgcn_mfma_f32_16x16x32_bf16(             \
          av[m4][1], bv[n2][1], acc[(mh)*4 + m4][(nh)*2 + n2], 0, 0, 0);                   \
    }                                                                                      \
    __builtin_amdgcn_s_setprio(0);                                                         \
  } while (0)
#define BAR __builtin_amdgcn_s_barrier()
#define VMC(n) asm volatile("s_waitcnt vmcnt(" #n ")" ::: "memory")

  const int KT = K >> 6;
  const int NIT = KT >> 1;

  STG(0, 0, 0, 0); STG(0, 0, 1, 0); STG(1, 0, 0, 0); STG(1, 0, 1, 0);
  STG(1, 1, 0, 1); STG(1, 1, 1, 1); STG(0, 1, 0, 1);
  VMC(6);
  BAR;

  for (int j = 0; j < NIT; ++j) {
    const bool full = (j < NIT - 1);
    RDA(0, 0); RDB(bv0, 0, 0);
    STG(0, 1, 1, 2 * j + 1);
    BAR; MFM(bv0, 0, 0); BAR;
    RDB(bv1, 0, 1);
    BAR; MFM(bv1, 0, 1); BAR;
    RDA(0, 1);
    if (full) STG(1, 0, 0, 2 * j + 2);
    BAR; MFM(bv1, 1, 1); BAR;
    if (full) {
      STG(0, 0, 0, 2 * j + 2); STG(1, 0, 1, 2 * j + 2);
      VMC(6);
    } else {
      VMC(0);
    }
    BAR; MFM(bv0, 1, 0); BAR;
    RDA(1, 0); RDB(bv0, 1, 0);
    if (full) STG(0, 0, 1, 2 * j + 2);
    BAR; MFM(bv0, 0, 0); BAR;
    RDB(bv1, 1, 1);
    BAR; MFM(bv1, 0, 1); BAR;
    RDA(1, 1);
    if (full) STG(1, 1, 0, 2 * j + 3);
    BAR; MFM(bv1, 1, 1); BAR;
    if (full) {
      STG(1, 1, 1, 2 * j + 3); STG(0, 1, 0, 2 * j + 3);
      VMC(6);
    }
    BAR; MFM(bv0, 1, 0); BAR;
  }

  const int rb = m0 + wm * 128 + (l >> 4) * 4;
  const int cb = n0 + wn * 64 + (l & 15);
#pragma unroll
  for (int m = 0; m < 8; ++m)
#pragma unroll
    for (int n = 0; n < 4; ++n)
#pragma unroll
      for (int i = 0; i < 4; ++i) {
        float v = acc[m][n][i] * alpha;
        long off = (long)(rb + m * 16 + i) * N + (cb + n * 16);
        if constexpr (sizeof(CT) == 2)
          C[off] = f2bf(v);
        else
          C[off] = v;
      }
#undef STG
#undef RDA
#undef RDB
#undef MFM
#undef BAR
#undef VMC
}

// ======================= 128^2 m97 BT GEMM (dense, for V^T) =================
template <typename CT>
__global__ __launch_bounds__(256) void k_gemm_bt(const unsigned short* __restrict__ A,
                                                 const unsigned short* __restrict__ B,
                                                 CT* __restrict__ C, int nx, int ny, int N, int K,
                                                 long sA, long sB, long sC, float alpha) {
  const unsigned bid = blockIdx.x;
  const unsigned cpx = gridDim.x >> 3;
  const unsigned logical = (bid & 7) * cpx + (bid >> 3);
  const int per_z = nx * ny;
  const int z = (int)(logical / per_z);
  const int r = (int)(logical - (unsigned)z * per_z);
  const int by = r / nx;
  const int bx = r - by * nx;
  const int m0 = by * 128;
  const int n0 = bx * 128;
  A += (long)z * sA;
  B += (long)z * sB;
  C += (long)z * sC;

  __shared__ unsigned short As[128 * 64];
  __shared__ unsigned short Bs[128 * 64];
  char* const AsB = (char*)As;
  char* const BsB = (char*)Bs;

  const int t = threadIdx.x;
  const int l = t & 63;
  const int w = t >> 6;
  const int wr = (w >> 1) * 64;
  const int wc = (w & 1) * 64;

  const int srow = t >> 3;
  const int sch = (t & 7) ^ (srow & 7);
  const unsigned short* Ag = A + (long)(m0 + srow) * K + sch * 8;
  const unsigned short* Bg = B + (long)(n0 + srow) * K + sch * 8;
  const int soff = t * 16;

  const int ar = wr + (l & 15);
  const int brr = wc + (l & 15);
  const int kc = l >> 4;

  f32x4 acc[4][4];
#pragma unroll
  for (int i = 0; i < 4; ++i)
#pragma unroll
    for (int j = 0; j < 4; ++j) acc[i][j] = f32x4{0.f, 0.f, 0.f, 0.f};

  const int KT = K >> 6;
  for (int kt = 0; kt < KT; ++kt) {
    const long ko = (long)kt * 64;
#pragma unroll
    for (int i = 0; i < 4; ++i) GLDS16(Ag + (long)i * 32 * K + ko, AsB + i * 4096 + soff);
#pragma unroll
    for (int i = 0; i < 4; ++i) GLDS16(Bg + (long)i * 32 * K + ko, BsB + i * 4096 + soff);
    __syncthreads();
#pragma unroll
    for (int kk = 0; kk < 2; ++kk) {
      bf16x8 av[4], bv[4];
#pragma unroll
      for (int m = 0; m < 4; ++m) {
        int rr = ar + m * 16;
        int c = (kk * 4 + kc) ^ (rr & 7);
        av[m] = *(const bf16x8*)(AsB + rr * 128 + c * 16);
      }
#pragma unroll
      for (int n = 0; n < 4; ++n) {
        int rr = brr + n * 16;
        int c = (kk * 4 + kc) ^ (rr & 7);
        bv[n] = *(const bf16x8*)(BsB + rr * 128 + c * 16);
      }
#pragma unroll
      for (int m = 0; m < 4; ++m)
#pragma unroll
        for (int n = 0; n < 4; ++n)
          acc[m][n] = __builtin_amdgcn_mfma_f32_16x16x32_bf16(av[m], bv[n], acc[m][n], 0, 0, 0);
    }
    __syncthreads();
  }

  const int rb = m0 + wr + (l >> 4) * 4;
  const int cb = n0 + wc + (l & 15);
#pragma unroll
  for (int m = 0; m < 4; ++m)
#pragma unroll
    for (int n = 0; n < 4; ++n)
#pragma unroll
      for (int i = 0; i < 4; ++i) {
        float v = acc[m][n][i] * alpha;
        long off = (long)(rb + m * 16 + i) * N + (cb + n * 16);
        if constexpr (sizeof(CT) == 2)
          C[off] = f2bf(v);
        else
          C[off] = v;
      }
}

// ======================= 128x64 BT GEMM, uniform-work modes =================
// BM=128, BN=64, BK=64; 4 waves 2x2, wave tile 64x32.
// MODE 0 (scores): 64-col triangular decode; single-buffered (24 KiB LDS,
//   ~5 blocks/CU — implicit overlap covers latency, m99/m100).
// MODE 1 (PV): fused row-pair (by, 15-by), 34 K-tiles/block uniform;
//   DBUF=1: double-buffered, counted vmcnt(6) 2-phase (grid = 2 blocks/CU,
//   implicit overlap too thin — hide HBM latency explicitly).
template <typename CT, int MODE, int DBUF>
__global__ __launch_bounds__(256) void k_gemm_bt64(const unsigned short* __restrict__ A,
                                                   const unsigned short* __restrict__ B,
                                                   CT* __restrict__ C, int N, int K, long sA,
                                                   long sB, long sC, float alpha) {
  const unsigned bid = blockIdx.x;
  const unsigned cpx = gridDim.x >> 3;
  const unsigned logical = (bid & 7) * cpx + (bid >> 3);
  int z, by, bx;
  if constexpr (MODE == 0) {
    const int per_z = 272;
    z = (int)(logical / per_z);
    int r = (int)(logical - (unsigned)z * per_z);
    int b = (int)((sqrtf(4.f * (float)r + 1.f) - 1.f) * 0.5f);
    while ((b + 1) * (b + 2) <= r) ++b;
    while (b * (b + 1) > r) --b;
    by = b;
    bx = r - b * (b + 1);
  } else {
    const int nx = N >> 6;
    const int per_z = 8 * nx;
    z = (int)(logical / per_z);
    int r = (int)(logical - (unsigned)z * per_z);
    by = r / nx;
    bx = r - by * nx;
  }
  A += (long)z * sA;
  B += (long)z * sB;
  C += (long)z * sC;

  __shared__ unsigned short As[(1 + DBUF) * 128 * 64];
  __shared__ unsigned short Bs[(1 + DBUF) * 64 * 64];
  char* const AsB = (char*)As;
  char* const BsB = (char*)Bs;

  const int t = threadIdx.x;
  const int l = t & 63;
  const int w = t >> 6;
  const int wr = (w >> 1) * 64;
  const int wc = (w & 1) * 32;

  const int srow = t >> 3;
  const int sch = (t & 7) ^ (srow & 7);
  const int soff = t * 16;

  const int ar = wr + (l & 15);
  const int brr = wc + (l & 15);
  const int kc = l >> 4;

  const int n0 = bx * 64;
  const unsigned short* Bg = B + (long)(n0 + srow) * K + sch * 8;

#define STG64(Agp, kt, bf)                                                           \
  do {                                                                               \
    const long ko = (long)(kt)*64;                                                   \
    _Pragma("unroll") for (int i = 0; i < 4; ++i)                                    \
        GLDS16((Agp) + (long)i * 32 * K + ko, AsB + (bf)*16384 + i * 4096 + soff);   \
    _Pragma("unroll") for (int i = 0; i < 2; ++i)                                    \
        GLDS16(Bg + (long)i * 32 * K + ko, BsB + (bf)*8192 + i * 4096 + soff);       \
  } while (0)

#define CMP64(bf)                                                                    \
  do {                                                                               \
    _Pragma("unroll") for (int kk = 0; kk < 2; ++kk) {                               \
      bf16x8 av[4], bv[2];                                                           \
      _Pragma("unroll") for (int m = 0; m < 4; ++m) {                                \
        int rr = ar + m * 16;                                                        \
        int c = (kk * 4 + kc) ^ (rr & 7);                                            \
        av[m] = *(const bf16x8*)(AsB + (bf)*16384 + rr * 128 + c * 16);              \
      }                                                                              \
      _Pragma("unroll") for (int n = 0; n < 2; ++n) {                                \
        int rr = brr + n * 16;                                                       \
        int c = (kk * 4 + kc) ^ (rr & 7);                                            \
        bv[n] = *(const bf16x8*)(BsB + (bf)*8192 + rr * 128 + c * 16);               \
      }                                                                              \
      _Pragma("unroll") for (int m = 0; m < 4; ++m) _Pragma("unroll") for (int n = 0; \
                                                                          n < 2; ++n) \
          acc[m][n] = __builtin_amdgcn_mfma_f32_16x16x32_bf16(av[m], bv[n], acc[m][n], 0, 0, 0); \
    }                                                                                \
  } while (0)

  const int nseg = (MODE == 1) ? 2 : 1;
  for (int seg = 0; seg < nseg; ++seg) {
    const int row = (MODE == 1) ? (seg ? (15 - by) : by) : by;
    const int m0 = row * 128;
    const int KT = (MODE == 1) ? ((m0 + 128) >> 6) : (K >> 6);
    const unsigned short* Ag = A + (long)(m0 + srow) * K + sch * 8;

    f32x4 acc[4][2];
#pragma unroll
    for (int i = 0; i < 4; ++i)
#pragma unroll
      for (int j = 0; j < 2; ++j) acc[i][j] = f32x4{0.f, 0.f, 0.f, 0.f};

    if constexpr (DBUF) {
      // 2-phase: STAGE(t+1); vmcnt(6) retires stage(t); BAR; COMPUTE(t); BAR
      STG64(Ag, 0, 0);
      for (int kt = 0; kt < KT; ++kt) {
        if (kt + 1 < KT) {
          STG64(Ag, kt + 1, (kt + 1) & 1);
          asm volatile("s_waitcnt vmcnt(6)" ::: "memory");
        } else {
          asm volatile("s_waitcnt vmcnt(0)" ::: "memory");
        }
        __builtin_amdgcn_s_barrier();
        CMP64(kt & 1);
        __builtin_amdgcn_s_barrier();
      }
    } else {
      for (int kt = 0; kt < KT; ++kt) {
        STG64(Ag, kt, 0);
        __syncthreads();
        CMP64(0);
        __syncthreads();
      }
    }

    const int rb = m0 + wr + (l >> 4) * 4;
    const int cb = n0 + wc + (l & 15);
#pragma unroll
    for (int m = 0; m < 4; ++m)
#pragma unroll
      for (int n = 0; n < 2; ++n)
#pragma unroll
        for (int i = 0; i < 4; ++i) {
          float v = acc[m][n][i] * alpha;
          long off = (long)(rb + m * 16 + i) * N + (cb + n * 16);
          if constexpr (sizeof(CT) == 2)
            C[off] = f2bf(v);
          else
            C[off] = v;
        }
  }
#undef STG64
#undef CMP64
}

// ---------------- causal row softmax, live-region only ----------------------
__global__ __launch_bounds__(256) void k_softmax(unsigned short* __restrict__ P, int S) {
  const int t = threadIdx.x;
  const int wv = t >> 6, l = t & 63;
  const int q = blockIdx.x * 4 + wv;
  unsigned short* row = P + ((long)blockIdx.y * S + q) * S;
  const int nch = (q >> 9) + 1;

  uint4 raw[4];
  float v[32];
#pragma unroll
  for (int j = 0; j < 4; ++j)
    if (j < nch) raw[j] = ((const uint4*)row)[j * 64 + l];
#pragma unroll
  for (int j = 0; j < 4; ++j) {
    if (j < nch) {
      unsigned int rw[4] = {raw[j].x, raw[j].y, raw[j].z, raw[j].w};
#pragma unroll
      for (int e = 0; e < 8; ++e)
        v[j * 8 + e] = bf2f((unsigned short)((rw[e >> 1] >> ((e & 1) * 16)) & 0xFFFF));
    }
  }

  float mx = -3.0e38f;
#pragma unroll
  for (int j = 0; j < 4; ++j)
    if (j < nch) {
#pragma unroll
      for (int e = 0; e < 8; ++e) {
        int col = j * 512 + l * 8 + e;
        if (col <= q) mx = fmaxf(mx, v[j * 8 + e]);
      }
    }
#pragma unroll
  for (int o = 32; o >= 1; o >>= 1) mx = fmaxf(mx, __shfl_xor(mx, o, 64));

  float s = 0.f;
#pragma unroll
  for (int j = 0; j < 4; ++j)
    if (j < nch) {
#pragma unroll
      for (int e = 0; e < 8; ++e) {
        int col = j * 512 + l * 8 + e;
        float ev = (col <= q) ? __expf(v[j * 8 + e] - mx) : 0.f;
        v[j * 8 + e] = ev;
        s += ev;
      }
    }
#pragma unroll
  for (int o = 32; o >= 1; o >>= 1) s += __shfl_xor(s, o, 64);
  const float inv = 1.f / s;

#pragma unroll
  for (int j = 0; j < 4; ++j)
    if (j < nch) {
      uint4 ow;
      unsigned int o2[4];
#pragma unroll
      for (int jj = 0; jj < 4; ++jj)
        o2[jj] = (unsigned)f2bf(v[j * 8 + 2 * jj] * inv) |
                 ((unsigned)f2bf(v[j * 8 + 2 * jj + 1] * inv) << 16);
      ow.x = o2[0]; ow.y = o2[1]; ow.z = o2[2]; ow.w = o2[3];
      ((uint4*)row)[j * 64 + l] = ow;
    }
}

// ---------------------------------------------------------------------------
extern "C" void kernel_launch(void* const* d_in, const int* in_sizes, int n_in, void* d_out,
                              int out_size, void* d_ws, size_t ws_size, hipStream_t stream) {
  const int B = 4, S = 2048, D = 1024;
  const long MS = (long)B * S;

  const float* x = (const float*)d_in[0];
  const float* Wq = (const float*)d_in[1];
  const float* Wk = (const float*)d_in[2];
  const float* Wv = (const float*)d_in[3];
  float* out = (float*)d_out;

  unsigned short* xb = (unsigned short*)d_ws;   // [8192][1024]
  unsigned short* Wt = xb + MS * D;             // 3 x [1024][1024] (transposed)
  unsigned short* Qb = Wt + 3L * D * D;         // [8192][1024]
  unsigned short* Kb = Qb + MS * D;             // [8192][1024]
  unsigned short* Vt = Kb + MS * D;             // 4 x [1024][2048]
  unsigned short* P  = Vt + MS * D;             // 4 x [2048][2048]
  (void)ws_size;

  long n = MS * D;
  const int ncvt = (int)(n / 8 / 256);                 // 4096
  const int ntrw = 3 * (D / 32) * (D / 32);            // 3072
  k_prep<<<ncvt + ntrw, 256, 0, stream>>>(x, xb, Wq, Wk, Wv, Wt, n, ncvt, D);
  // Q,K projections (8-phase 256^2): nwg = 4*32*2 = 256
  k_gemm256<unsigned short><<<256, 512, 0, stream>>>(
      xb, Wt, Qb, /*nx=*/D / 256, /*ny=*/(int)(MS / 256), /*N=*/D, /*K=*/D,
      /*sA=*/0L, /*sB=*/(long)D * D, /*sC=*/MS * D, 1.0f);
  // V^T direct: Vt[f][s] = sum_k Wv^T[f][k] * xb_b[s][k]   (nwg = 16*8*4 = 512)
  k_gemm_bt<unsigned short><<<512, 256, 0, stream>>>(
      Wt + 2L * D * D, xb, Vt, /*nx=*/S / 128, /*ny=*/D / 128, /*N=*/S, /*K=*/D,
      /*sA=*/0L, /*sB=*/(long)S * D, /*sC=*/(long)D * S, 1.0f);
  // scores: 64-col triangular, uniform blocks (nwg = 4*272 = 1088)
  k_gemm_bt64<unsigned short, 0, 0><<<1088, 256, 0, stream>>>(
      Qb, Kb, P, /*N=*/S, /*K=*/D,
      /*sA=*/(long)S * D, /*sB=*/(long)S * D, /*sC=*/(long)S * S, 0.03125f);
  // causal softmax (live region only)
  k_softmax<<<dim3(S / 4, B), 256, 0, stream>>>(P, S);
  // PV: fused row-pairs, 34 K-tiles/block uniform, 2-phase dbuf (nwg = 512)
  k_gemm_bt64<float, 1, 1><<<512, 256, 0, stream>>>(
      P, Vt, out, /*N=*/D, /*K=*/S,
      /*sA=*/(long)S * S, /*sB=*/(long)D * S, /*sC=*/(long)S * D, 1.0f);
}

// Round 8
// 139.201 us; speedup vs baseline: 1.3726x; 1.0194x over previous
//
#include <hip/hip_runtime.h>

// ---------------------------------------------------------------------------
// CausalAttention: out = softmax(mask(QK^T/sqrt(D))) @ V,  Q/K/V = x @ W_{q,k,v}
// B=4, S=2048, D_IN=D_OUT=1024, fp32 in/out, bf16 MFMA internally.
// R8: Vt GEMM gets 2-phase dbuf + vmcnt(8) (2 blocks/CU regime, same fix as
// PV's R7); PV pipeline deepened to 3 buffers / vmcnt(12) — per-tile compute
// (~100 cyc/SIMD) is far below HBM latency (~600 cyc), so depth-1 was
// insufficient. Scores stays single-buffered (4.25 blocks/CU TLP regime).
// ---------------------------------------------------------------------------

typedef __bf16 bf16x8 __attribute__((ext_vector_type(8)));
typedef float f32x4 __attribute__((ext_vector_type(4)));

__device__ __forceinline__ unsigned short f2bf(float f) {
  unsigned int u = __builtin_bit_cast(unsigned int, f);
  u += 0x7FFFu + ((u >> 16) & 1u);  // RNE
  return (unsigned short)(u >> 16);
}
__device__ __forceinline__ float bf2f(unsigned short h) {
  unsigned int u = ((unsigned int)h) << 16;
  return __builtin_bit_cast(float, u);
}

#define GLDS16(g, l)                                                                   \
  __builtin_amdgcn_global_load_lds((const __attribute__((address_space(1))) void*)(g), \
                                   (__attribute__((address_space(3))) void*)(l), 16, 0, 0)

// ---------------- merged: fp32->bf16 convert + W transpose ------------------
__global__ __launch_bounds__(256) void k_prep(const float* __restrict__ x,
                                              unsigned short* __restrict__ xb,
                                              const float* __restrict__ W0,
                                              const float* __restrict__ W1,
                                              const float* __restrict__ W2,
                                              unsigned short* __restrict__ Wt, long n, int ncvt,
                                              int D) {
  const int b = blockIdx.x;
  const int t = threadIdx.x;
  if (b < ncvt) {
    long i = ((long)b * 256 + t) * 8;
    if (i >= n) return;
    float4 a = *(const float4*)(x + i);
    float4 c = *(const float4*)(x + i + 4);
    uint4 o;
    o.x = (unsigned)f2bf(a.x) | ((unsigned)f2bf(a.y) << 16);
    o.y = (unsigned)f2bf(a.z) | ((unsigned)f2bf(a.w) << 16);
    o.z = (unsigned)f2bf(c.x) | ((unsigned)f2bf(c.y) << 16);
    o.w = (unsigned)f2bf(c.z) | ((unsigned)f2bf(c.w) << 16);
    *(uint4*)(xb + i) = o;
    return;
  }
  const int id = b - ncvt;
  const int nt = (D / 32) * (D / 32);
  const int z = id / nt;
  const int rem = id - z * nt;
  const int by = (rem >> 5) * 32, bx = (rem & 31) * 32;
  const float* W = z == 0 ? W0 : (z == 1 ? W1 : W2);
  unsigned short* out = Wt + (long)z * D * D;
  __shared__ float tile[32][33];
  const int tx = t & 31, ty = t >> 5;
#pragma unroll
  for (int j = 0; j < 4; ++j) tile[ty + j * 8][tx] = W[(long)(by + ty + j * 8) * D + bx + tx];
  __syncthreads();
#pragma unroll
  for (int j = 0; j < 4; ++j)
    out[(long)(bx + ty + j * 8) * D + by + tx] = f2bf(tile[tx][ty + j * 8]);
}

// ======================= 256^2 8-phase BT GEMM (projections) ================
template <typename CT>
__global__ __launch_bounds__(512, 2) void k_gemm256(const unsigned short* __restrict__ A,
                                                    const unsigned short* __restrict__ B,
                                                    CT* __restrict__ C, int nx, int ny, int N,
                                                    int K, long sA, long sB, long sC,
                                                    float alpha) {
  const unsigned bid = blockIdx.x;
  const unsigned cpx = gridDim.x >> 3;
  const unsigned logical = (bid & 7) * cpx + (bid >> 3);
  const int per_z = nx * ny;
  const int z = (int)(logical / per_z);
  const int rem = (int)(logical - (unsigned)z * per_z);
  const int by = rem / nx;
  const int bx = rem - by * nx;
  const int m0 = by * 256, n0 = bx * 256;
  A += (long)z * sA;
  B += (long)z * sB;
  C += (long)z * sC;

  __shared__ char lds[131072];

  const int t = threadIdx.x;
  const int l = t & 63;
  const int w = t >> 6;
  const int wm = w >> 2;
  const int wn = w & 3;

  const int srow = t >> 3;
  const int sch = (t & 7) ^ (srow & 7);
  const int soff = t * 16;

#define STG(mat, bf, hf, kt)                                                              \
  do {                                                                                    \
    const unsigned short* g =                                                             \
        ((mat) ? B + (long)(n0 + (hf)*128 + srow) * K : A + (long)(m0 + (hf)*128 + srow) * K) + \
        (long)(kt)*64 + sch * 8;                                                          \
    char* d = lds + (mat)*65536 + (bf)*32768 + (hf)*16384 + soff;                         \
    GLDS16(g, d);                                                                         \
    GLDS16(g + (long)64 * K, d + 8192);                                                   \
  } while (0)

  const int lx = l & 15;
  const int kx0 = ((l >> 4) ^ (l & 7)) * 16;
  const int kx1 = ((4 + (l >> 4)) ^ (l & 7)) * 16;
  char* const aB = lds + wm * 16384 + lx * 128;
  char* const bB = lds + 65536 + (wn >> 1) * 16384 + ((wn & 1) * 64 + lx) * 128;

  bf16x8 av[4][2], bv0[2][2], bv1[2][2];
  f32x4 acc[8][4];
#pragma unroll
  for (int i = 0; i < 8; ++i)
#pragma unroll
    for (int jn = 0; jn < 4; ++jn) acc[i][jn] = f32x4{0.f, 0.f, 0.f, 0.f};

#define RDA(bf, mh)                                                     \
  do {                                                                  \
    _Pragma("unroll") for (int m4 = 0; m4 < 4; ++m4) {                  \
      char* p = aB + (bf)*32768 + ((mh)*64 + m4 * 16) * 128;            \
      av[m4][0] = *(const bf16x8*)(p + kx0);                            \
      av[m4][1] = *(const bf16x8*)(p + kx1);                            \
    }                                                                   \
  } while (0)
#define RDB(dst, bf, nh)                                                \
  do {                                                                  \
    _Pragma("unroll") for (int n2 = 0; n2 < 2; ++n2) {                  \
      char* p = bB + (bf)*32768 + (((nh)*2 + n2) * 16) * 128;           \
      dst[n2][0] = *(const bf16x8*)(p + kx0);                           \
      dst[n2][1] = *(const bf16x8*)(p + kx1);                           \
    }                                                                   \
  } while (0)
#define MFM(bv, mh, nh)                                                                    \
  do {                                                                                     \
    __builtin_amdgcn_s_setprio(1);                                                         \
    _Pragma("unroll") for (int m4 = 0; m4 < 4; ++m4) _Pragma("unroll") for (int n2 = 0;    \
                                                                            n2 < 2; ++n2) { \
      acc[(mh)*4 + m4][(nh)*2 + n2] = __builtin_amdgcn_mfma_f32_16x16x32_bf16(             \
          av[m4][0], bv[n2][0], acc[(mh)*4 + m4][(nh)*2 + n2], 0, 0, 0);                   \
      acc[(mh)*4 + m4][(nh)*2 + n2] = __builtin_amdgcn_mfma_f32_16x16x32_bf16(             \
          av[m4][1], bv[n2][1], acc[(mh)*4 + m4][(nh)*2 + n2], 0, 0, 0);                   \
    }                                                                                      \
    __builtin_amdgcn_s_setprio(0);                                                         \
  } while (0)
#define BAR __builtin_amdgcn_s_barrier()
#define VMC(n) asm volatile("s_waitcnt vmcnt(" #n ")" ::: "memory")

  const int KT = K >> 6;
  const int NIT = KT >> 1;

  STG(0, 0, 0, 0); STG(0, 0, 1, 0); STG(1, 0, 0, 0); STG(1, 0, 1, 0);
  STG(1, 1, 0, 1); STG(1, 1, 1, 1); STG(0, 1, 0, 1);
  VMC(6);
  BAR;

  for (int j = 0; j < NIT; ++j) {
    const bool full = (j < NIT - 1);
    RDA(0, 0); RDB(bv0, 0, 0);
    STG(0, 1, 1, 2 * j + 1);
    BAR; MFM(bv0, 0, 0); BAR;
    RDB(bv1, 0, 1);
    BAR; MFM(bv1, 0, 1); BAR;
    RDA(0, 1);
    if (full) STG(1, 0, 0, 2 * j + 2);
    BAR; MFM(bv1, 1, 1); BAR;
    if (full) {
      STG(0, 0, 0, 2 * j + 2); STG(1, 0, 1, 2 * j + 2);
      VMC(6);
    } else {
      VMC(0);
    }
    BAR; MFM(bv0, 1, 0); BAR;
    RDA(1, 0); RDB(bv0, 1, 0);
    if (full) STG(0, 0, 1, 2 * j + 2);
    BAR; MFM(bv0, 0, 0); BAR;
    RDB(bv1, 1, 1);
    BAR; MFM(bv1, 0, 1); BAR;
    RDA(1, 1);
    if (full) STG(1, 1, 0, 2 * j + 3);
    BAR; MFM(bv1, 1, 1); BAR;
    if (full) {
      STG(1, 1, 1, 2 * j + 3); STG(0, 1, 0, 2 * j + 3);
      VMC(6);
    }
    BAR; MFM(bv0, 1, 0); BAR;
  }

  const int rb = m0 + wm * 128 + (l >> 4) * 4;
  const int cb = n0 + wn * 64 + (l & 15);
#pragma unroll
  for (int m = 0; m < 8; ++m)
#pragma unroll
    for (int n = 0; n < 4; ++n)
#pragma unroll
      for (int i = 0; i < 4; ++i) {
        float v = acc[m][n][i] * alpha;
        long off = (long)(rb + m * 16 + i) * N + (cb + n * 16);
        if constexpr (sizeof(CT) == 2)
          C[off] = f2bf(v);
        else
          C[off] = v;
      }
#undef STG
#undef RDA
#undef RDB
#undef MFM
#undef BAR
#undef VMC
}

// ======================= 128^2 BT GEMM, 2-phase dbuf (V^T) ==================
// 512 blocks = 2 blocks/CU: implicit overlap too thin -> explicit dbuf with
// counted vmcnt(8) (8 staging loads/thread; stage(t+1) in flight across bar).
template <typename CT>
__global__ __launch_bounds__(256) void k_gemm_bt(const unsigned short* __restrict__ A,
                                                 const unsigned short* __restrict__ B,
                                                 CT* __restrict__ C, int nx, int ny, int N, int K,
                                                 long sA, long sB, long sC, float alpha) {
  const unsigned bid = blockIdx.x;
  const unsigned cpx = gridDim.x >> 3;
  const unsigned logical = (bid & 7) * cpx + (bid >> 3);
  const int per_z = nx * ny;
  const int z = (int)(logical / per_z);
  const int r = (int)(logical - (unsigned)z * per_z);
  const int by = r / nx;
  const int bx = r - by * nx;
  const int m0 = by * 128;
  const int n0 = bx * 128;
  A += (long)z * sA;
  B += (long)z * sB;
  C += (long)z * sC;

  __shared__ unsigned short As[2 * 128 * 64];
  __shared__ unsigned short Bs[2 * 128 * 64];
  char* const AsB = (char*)As;
  char* const BsB = (char*)Bs;

  const int t = threadIdx.x;
  const int l = t & 63;
  const int w = t >> 6;
  const int wr = (w >> 1) * 64;
  const int wc = (w & 1) * 64;

  const int srow = t >> 3;
  const int sch = (t & 7) ^ (srow & 7);
  const unsigned short* Ag = A + (long)(m0 + srow) * K + sch * 8;
  const unsigned short* Bg = B + (long)(n0 + srow) * K + sch * 8;
  const int soff = t * 16;

  const int ar = wr + (l & 15);
  const int brr = wc + (l & 15);
  const int kc = l >> 4;

  f32x4 acc[4][4];
#pragma unroll
  for (int i = 0; i < 4; ++i)
#pragma unroll
    for (int j = 0; j < 4; ++j) acc[i][j] = f32x4{0.f, 0.f, 0.f, 0.f};

#define STGBT(kt, bf)                                                                     \
  do {                                                                                    \
    const long ko = (long)(kt)*64;                                                        \
    _Pragma("unroll") for (int i = 0; i < 4; ++i)                                         \
        GLDS16(Ag + (long)i * 32 * K + ko, AsB + (bf)*16384 + i * 4096 + soff);           \
    _Pragma("unroll") for (int i = 0; i < 4; ++i)                                         \
        GLDS16(Bg + (long)i * 32 * K + ko, BsB + (bf)*16384 + i * 4096 + soff);           \
  } while (0)

  const int KT = K >> 6;
  STGBT(0, 0);
  for (int kt = 0; kt < KT; ++kt) {
    if (kt + 1 < KT) {
      STGBT(kt + 1, (kt + 1) & 1);
      asm volatile("s_waitcnt vmcnt(8)" ::: "memory");
    } else {
      asm volatile("s_waitcnt vmcnt(0)" ::: "memory");
    }
    __builtin_amdgcn_s_barrier();
    const int bf = kt & 1;
#pragma unroll
    for (int kk = 0; kk < 2; ++kk) {
      bf16x8 av[4], bv[4];
#pragma unroll
      for (int m = 0; m < 4; ++m) {
        int rr = ar + m * 16;
        int c = (kk * 4 + kc) ^ (rr & 7);
        av[m] = *(const bf16x8*)(AsB + bf * 16384 + rr * 128 + c * 16);
      }
#pragma unroll
      for (int n = 0; n < 4; ++n) {
        int rr = brr + n * 16;
        int c = (kk * 4 + kc) ^ (rr & 7);
        bv[n] = *(const bf16x8*)(BsB + bf * 16384 + rr * 128 + c * 16);
      }
#pragma unroll
      for (int m = 0; m < 4; ++m)
#pragma unroll
        for (int n = 0; n < 4; ++n)
          acc[m][n] = __builtin_amdgcn_mfma_f32_16x16x32_bf16(av[m], bv[n], acc[m][n], 0, 0, 0);
    }
    __builtin_amdgcn_s_barrier();
  }
#undef STGBT

  const int rb = m0 + wr + (l >> 4) * 4;
  const int cb = n0 + wc + (l & 15);
#pragma unroll
  for (int m = 0; m < 4; ++m)
#pragma unroll
    for (int n = 0; n < 4; ++n)
#pragma unroll
      for (int i = 0; i < 4; ++i) {
        float v = acc[m][n][i] * alpha;
        long off = (long)(rb + m * 16 + i) * N + (cb + n * 16);
        if constexpr (sizeof(CT) == 2)
          C[off] = f2bf(v);
        else
          C[off] = v;
      }
}

// ======================= 128x64 BT GEMM, uniform-work modes =================
// MODE 0 (scores): single-buffered, 4.25 blocks/CU TLP regime.
// MODE 1 (PV): 3-buffer depth-2 pipeline, vmcnt(12)/(6)/(0) ledger; 72 KiB
//   LDS -> 2 blocks/CU = grid demand.
template <typename CT, int MODE>
__global__ __launch_bounds__(256) void k_gemm_bt64(const unsigned short* __restrict__ A,
                                                   const unsigned short* __restrict__ B,
                                                   CT* __restrict__ C, int N, int K, long sA,
                                                   long sB, long sC, float alpha) {
  const unsigned bid = blockIdx.x;
  const unsigned cpx = gridDim.x >> 3;
  const unsigned logical = (bid & 7) * cpx + (bid >> 3);
  int z, by, bx;
  if constexpr (MODE == 0) {
    const int per_z = 272;
    z = (int)(logical / per_z);
    int r = (int)(logical - (unsigned)z * per_z);
    int b = (int)((sqrtf(4.f * (float)r + 1.f) - 1.f) * 0.5f);
    while ((b + 1) * (b + 2) <= r) ++b;
    while (b * (b + 1) > r) --b;
    by = b;
    bx = r - b * (b + 1);
  } else {
    const int nx = N >> 6;
    const int per_z = 8 * nx;
    z = (int)(logical / per_z);
    int r = (int)(logical - (unsigned)z * per_z);
    by = r / nx;
    bx = r - by * nx;
  }
  A += (long)z * sA;
  B += (long)z * sB;
  C += (long)z * sC;

  __shared__ unsigned short As[(MODE == 1 ? 3 : 1) * 128 * 64];
  __shared__ unsigned short Bs[(MODE == 1 ? 3 : 1) * 64 * 64];
  char* const AsB = (char*)As;
  char* const BsB = (char*)Bs;

  const int t = threadIdx.x;
  const int l = t & 63;
  const int w = t >> 6;
  const int wr = (w >> 1) * 64;
  const int wc = (w & 1) * 32;

  const int srow = t >> 3;
  const int sch = (t & 7) ^ (srow & 7);
  const int soff = t * 16;

  const int ar = wr + (l & 15);
  const int brr = wc + (l & 15);
  const int kc = l >> 4;

  const int n0 = bx * 64;
  const unsigned short* Bg = B + (long)(n0 + srow) * K + sch * 8;

#define STG64(Agp, kt, bf)                                                           \
  do {                                                                               \
    const long ko = (long)(kt)*64;                                                   \
    _Pragma("unroll") for (int i = 0; i < 4; ++i)                                    \
        GLDS16((Agp) + (long)i * 32 * K + ko, AsB + (bf)*16384 + i * 4096 + soff);   \
    _Pragma("unroll") for (int i = 0; i < 2; ++i)                                    \
        GLDS16(Bg + (long)i * 32 * K + ko, BsB + (bf)*8192 + i * 4096 + soff);       \
  } while (0)

#define CMP64(bf)                                                                    \
  do {                                                                               \
    _Pragma("unroll") for (int kk = 0; kk < 2; ++kk) {                               \
      bf16x8 av[4], bv[2];                                                           \
      _Pragma("unroll") for (int m = 0; m < 4; ++m) {                                \
        int rr = ar + m * 16;                                                        \
        int c = (kk * 4 + kc) ^ (rr & 7);                                            \
        av[m] = *(const bf16x8*)(AsB + (bf)*16384 + rr * 128 + c * 16);              \
      }                                                                              \
      _Pragma("unroll") for (int n = 0; n < 2; ++n) {                                \
        int rr = brr + n * 16;                                                       \
        int c = (kk * 4 + kc) ^ (rr & 7);                                            \
        bv[n] = *(const bf16x8*)(BsB + (bf)*8192 + rr * 128 + c * 16);               \
      }                                                                              \
      _Pragma("unroll") for (int m = 0; m < 4; ++m) _Pragma("unroll") for (int n = 0; \
                                                                          n < 2; ++n) \
          acc[m][n] = __builtin_amdgcn_mfma_f32_16x16x32_bf16(av[m], bv[n], acc[m][n], 0, 0, 0); \
    }                                                                                \
  } while (0)

  const int nseg = (MODE == 1) ? 2 : 1;
  for (int seg = 0; seg < nseg; ++seg) {
    const int row = (MODE == 1) ? (seg ? (15 - by) : by) : by;
    const int m0 = row * 128;
    const int KT = (MODE == 1) ? ((m0 + 128) >> 6) : (K >> 6);
    const unsigned short* Ag = A + (long)(m0 + srow) * K + sch * 8;

    f32x4 acc[4][2];
#pragma unroll
    for (int i = 0; i < 4; ++i)
#pragma unroll
      for (int j = 0; j < 2; ++j) acc[i][j] = f32x4{0.f, 0.f, 0.f, 0.f};

    if constexpr (MODE == 1) {
      // depth-2: stages t+1, t+2 in flight; vmcnt(12) retires stage(t).
      STG64(Ag, 0, 0);
      STG64(Ag, 1, 1);  // KT >= 2 always (min row pair K-tiles = 2)
      for (int kt = 0; kt < KT; ++kt) {
        if (kt + 2 < KT) {
          STG64(Ag, kt + 2, (kt + 2) % 3);
          asm volatile("s_waitcnt vmcnt(12)" ::: "memory");
        } else if (kt + 1 < KT) {
          asm volatile("s_waitcnt vmcnt(6)" ::: "memory");
        } else {
          asm volatile("s_waitcnt vmcnt(0)" ::: "memory");
        }
        __builtin_amdgcn_s_barrier();
        CMP64(kt % 3);
        __builtin_amdgcn_s_barrier();
      }
    } else {
      const int KT0 = KT;
      for (int kt = 0; kt < KT0; ++kt) {
        STG64(Ag, kt, 0);
        __syncthreads();
        CMP64(0);
        __syncthreads();
      }
    }

    const int rb = m0 + wr + (l >> 4) * 4;
    const int cb = n0 + wc + (l & 15);
#pragma unroll
    for (int m = 0; m < 4; ++m)
#pragma unroll
      for (int n = 0; n < 2; ++n)
#pragma unroll
        for (int i = 0; i < 4; ++i) {
          float v = acc[m][n][i] * alpha;
          long off = (long)(rb + m * 16 + i) * N + (cb + n * 16);
          if constexpr (sizeof(CT) == 2)
            C[off] = f2bf(v);
          else
            C[off] = v;
        }
  }
#undef STG64
#undef CMP64
}

// ---------------- causal row softmax, live-region only ----------------------
__global__ __launch_bounds__(256) void k_softmax(unsigned short* __restrict__ P, int S) {
  const int t = threadIdx.x;
  const int wv = t >> 6, l = t & 63;
  const int q = blockIdx.x * 4 + wv;
  unsigned short* row = P + ((long)blockIdx.y * S + q) * S;
  const int nch = (q >> 9) + 1;

  uint4 raw[4];
  float v[32];
#pragma unroll
  for (int j = 0; j < 4; ++j)
    if (j < nch) raw[j] = ((const uint4*)row)[j * 64 + l];
#pragma unroll
  for (int j = 0; j < 4; ++j) {
    if (j < nch) {
      unsigned int rw[4] = {raw[j].x, raw[j].y, raw[j].z, raw[j].w};
#pragma unroll
      for (int e = 0; e < 8; ++e)
        v[j * 8 + e] = bf2f((unsigned short)((rw[e >> 1] >> ((e & 1) * 16)) & 0xFFFF));
    }
  }

  float mx = -3.0e38f;
#pragma unroll
  for (int j = 0; j < 4; ++j)
    if (j < nch) {
#pragma unroll
      for (int e = 0; e < 8; ++e) {
        int col = j * 512 + l * 8 + e;
        if (col <= q) mx = fmaxf(mx, v[j * 8 + e]);
      }
    }
#pragma unroll
  for (int o = 32; o >= 1; o >>= 1) mx = fmaxf(mx, __shfl_xor(mx, o, 64));

  float s = 0.f;
#pragma unroll
  for (int j = 0; j < 4; ++j)
    if (j < nch) {
#pragma unroll
      for (int e = 0; e < 8; ++e) {
        int col = j * 512 + l * 8 + e;
        float ev = (col <= q) ? __expf(v[j * 8 + e] - mx) : 0.f;
        v[j * 8 + e] = ev;
        s += ev;
      }
    }
#pragma unroll
  for (int o = 32; o >= 1; o >>= 1) s += __shfl_xor(s, o, 64);
  const float inv = 1.f / s;

#pragma unroll
  for (int j = 0; j < 4; ++j)
    if (j < nch) {
      uint4 ow;
      unsigned int o2[4];
#pragma unroll
      for (int jj = 0; jj < 4; ++jj)
        o2[jj] = (unsigned)f2bf(v[j * 8 + 2 * jj] * inv) |
                 ((unsigned)f2bf(v[j * 8 + 2 * jj + 1] * inv) << 16);
      ow.x = o2[0]; ow.y = o2[1]; ow.z = o2[2]; ow.w = o2[3];
      ((uint4*)row)[j * 64 + l] = ow;
    }
}

// ---------------------------------------------------------------------------
extern "C" void kernel_launch(void* const* d_in, const int* in_sizes, int n_in, void* d_out,
                              int out_size, void* d_ws, size_t ws_size, hipStream_t stream) {
  const int B = 4, S = 2048, D = 1024;
  const long MS = (long)B * S;

  const float* x = (const float*)d_in[0];
  const float* Wq = (const float*)d_in[1];
  const float* Wk = (const float*)d_in[2];
  const float* Wv = (const float*)d_in[3];
  float* out = (float*)d_out;

  unsigned short* xb = (unsigned short*)d_ws;   // [8192][1024]
  unsigned short* Wt = xb + MS * D;             // 3 x [1024][1024] (transposed)
  unsigned short* Qb = Wt + 3L * D * D;         // [8192][1024]
  unsigned short* Kb = Qb + MS * D;             // [8192][1024]
  unsigned short* Vt = Kb + MS * D;             // 4 x [1024][2048]
  unsigned short* P  = Vt + MS * D;             // 4 x [2048][2048]
  (void)ws_size;

  long n = MS * D;
  const int ncvt = (int)(n / 8 / 256);
  const int ntrw = 3 * (D / 32) * (D / 32);
  k_prep<<<ncvt + ntrw, 256, 0, stream>>>(x, xb, Wq, Wk, Wv, Wt, n, ncvt, D);
  // Q,K projections (8-phase 256^2): nwg = 4*32*2 = 256
  k_gemm256<unsigned short><<<256, 512, 0, stream>>>(
      xb, Wt, Qb, /*nx=*/D / 256, /*ny=*/(int)(MS / 256), /*N=*/D, /*K=*/D,
      /*sA=*/0L, /*sB=*/(long)D * D, /*sC=*/MS * D, 1.0f);
  // V^T direct (2-phase dbuf): nwg = 16*8*4 = 512
  k_gemm_bt<unsigned short><<<512, 256, 0, stream>>>(
      Wt + 2L * D * D, xb, Vt, /*nx=*/S / 128, /*ny=*/D / 128, /*N=*/S, /*K=*/D,
      /*sA=*/0L, /*sB=*/(long)S * D, /*sC=*/(long)D * S, 1.0f);
  // scores: 64-col triangular, uniform blocks (nwg = 4*272 = 1088)
  k_gemm_bt64<unsigned short, 0><<<1088, 256, 0, stream>>>(
      Qb, Kb, P, /*N=*/S, /*K=*/D,
      /*sA=*/(long)S * D, /*sB=*/(long)S * D, /*sC=*/(long)S * S, 0.03125f);
  // causal softmax (live region only)
  k_softmax<<<dim3(S / 4, B), 256, 0, stream>>>(P, S);
  // PV: fused row-pairs, depth-2 pipeline (nwg = 4*8*16 = 512)
  k_gemm_bt64<float, 1><<<512, 256, 0, stream>>>(
      P, Vt, out, /*N=*/D, /*K=*/S,
      /*sA=*/(long)S * S, /*sB=*/(long)D * S, /*sC=*/(long)S * D, 1.0f);
}